// Round 16
// baseline (130.400 us; speedup 1.0000x reference)
//
#include <hip/hip_runtime.h>
#include <hip/hip_bf16.h>

typedef __hip_bfloat16 bf16;
typedef __attribute__((ext_vector_type(8))) short s8b;   // 8 bf16 (4 VGPR)
typedef __attribute__((ext_vector_type(4))) float f4;    // MFMA C/D

#define B_ 2
#define TIN_ 12
#define N_ 800
#define F_ 2
#define H_ 6
#define D_ 8
#define C_ 48
#define TP_ 10
#define KW_ 14
#define SCALE 0.35355339059327373f  // 1/sqrt(8)
#define LOG2E 1.4426950408889634f

__device__ __forceinline__ float sigm(float x) { return 1.0f / (1.0f + __expf(-x)); }
__device__ __forceinline__ float tanh_(float x) {
  float e = __expf(-2.0f * x);
  return 2.0f / (1.0f + e) - 1.0f;
}
__device__ __forceinline__ float exp2_(float x) { return __builtin_amdgcn_exp2f(x); }
__device__ __forceinline__ float bfu(unsigned short u) {
  return __uint_as_float((unsigned)u << 16);
}
__device__ __forceinline__ unsigned short f2u(float v) {
  return __bfloat16_as_ushort(__float2bfloat16(v));
}
__device__ __forceinline__ float ldc(const float* p, size_t i) { return p[i]; }
__device__ __forceinline__ float ldc(const bf16* p, size_t i) { return __bfloat162float(p[i]); }
__device__ __forceinline__ void sto(float* p, size_t i, float v) { p[i] = v; }
__device__ __forceinline__ void sto(bf16* p, size_t i, float v) { p[i] = __float2bfloat16(v); }
__device__ __forceinline__ void gll16(const void* g, void* l) {
  __builtin_amdgcn_global_load_lds(
      (__attribute__((address_space(1))) void*)(g),
      (__attribute__((address_space(3))) void*)(l), 16, 0, 0);
}
// per-wave dtype detection: f32 data -> low bf16 halves have wild exponents
__device__ __forceinline__ int detect_f32(const void* xv) {
  const unsigned int* xw = (const unsigned int*)xv;
  unsigned int w = xw[threadIdx.x & 63];
  int e = (w >> 7) & 0xFF;
  int bad = ((e >= 1 && e < 96) || (e > 150)) ? 1 : 0;
  unsigned long long m = __ballot(bad);
  return (__popcll(m) >= 16) ? 1 : 0;
}

// ---------------- pack body: compact MFMA B-fragments ----------------------
template <typename TI>
__device__ __forceinline__ void pack_body(
    int gid, const TI* xwz, const TI* xwr, const TI* xwh,
    const TI* lwz, const TI* lwr, const TI* lwh, bf16* pwb) {
  const int total = 21 * 9216;
  if (gid >= total) return;
  int step = gid / 9216, r = gid % 9216;
  int g = r / 3072;  r %= 3072;
  int nt = r / 1024; r %= 1024;
  int c = r / 512;   r %= 512;
  int lane = r / 8, j = r % 8;
  int k = 32 * c + (lane >> 4) * 8 + j;
  int n = nt * 16 + (lane & 15);
  float v = 0.f;
  if (k < 48) {
    if (step < 11) {
      int t = step + 1;
      const TI* w = (g == 0) ? xwz : (g == 1) ? xwr : xwh;
      v = ldc(w, ((size_t)t * 144 + 96 + k) * 48 + n);
    } else {
      int t = step - 11;
      const TI* w = (g == 0) ? lwz : (g == 1) ? lwr : lwh;
      v = ldc(w, ((size_t)t * 96 + 48 + k) * 48 + n);
    }
  }
  pwb[gid] = __float2bfloat16(v);
}

// ---------------- temporal body (per-element gid) --------------------------
template <typename TI>
__device__ __forceinline__ void temporal_body(
    int gid, const TI* x, const TI* Wq, const TI* Wk, const TI* Wv,
    const TI* bq, const TI* bk, const TI* bv, bf16* att_t) {
  const int total = B_ * (TIN_ - 1) * H_ * N_;
  if (gid >= total) return;
  int n = gid % N_;
  int r = gid / N_;
  int h = r % H_;  r /= H_;
  int t = (r % (TIN_ - 1)) + 1;
  int b = r / (TIN_ - 1);

  float wq[F_][D_], wk[F_][D_], wv[F_][D_], bqv[D_], bkv[D_], bvv[D_];
#pragma unroll
  for (int f = 0; f < F_; ++f)
#pragma unroll
    for (int d = 0; d < D_; ++d) {
      wq[f][d] = ldc(Wq, (h * F_ + f) * D_ + d);
      wk[f][d] = ldc(Wk, (h * F_ + f) * D_ + d);
      wv[f][d] = ldc(Wv, (h * F_ + f) * D_ + d);
    }
#pragma unroll
  for (int d = 0; d < D_; ++d) {
    bqv[d] = ldc(bq, h * D_ + d);
    bkv[d] = ldc(bk, h * D_ + d);
    bvv[d] = ldc(bv, h * D_ + d);
  }
  float xt0 = ldc(x, ((b * TIN_ + t) * N_ + n) * F_ + 0);
  float xt1 = ldc(x, ((b * TIN_ + t) * N_ + n) * F_ + 1);
  float q[D_];
#pragma unroll
  for (int d = 0; d < D_; ++d) q[d] = xt0 * wq[0][d] + xt1 * wq[1][d] + bqv[d];

  float sc[TIN_];
  float mx = -1e30f;
#pragma unroll
  for (int s = 0; s < TIN_; ++s) {
    float xs0 = ldc(x, ((b * TIN_ + s) * N_ + n) * F_ + 0);
    float xs1 = ldc(x, ((b * TIN_ + s) * N_ + n) * F_ + 1);
    float dot = 0.f;
#pragma unroll
    for (int d = 0; d < D_; ++d)
      dot += q[d] * (xs0 * wk[0][d] + xs1 * wk[1][d] + bkv[d]);
    dot *= SCALE;
    sc[s] = (s <= t) ? dot : -1e30f;
    mx = fmaxf(mx, sc[s]);
  }
  float sum = 0.f;
#pragma unroll
  for (int s = 0; s < TIN_; ++s) {
    float p = __expf(sc[s] - mx);
    sc[s] = p;
    sum += p;
  }
  float inv = 1.0f / sum;
  float acc[D_];
#pragma unroll
  for (int d = 0; d < D_; ++d) acc[d] = 0.f;
#pragma unroll
  for (int s = 0; s < TIN_; ++s) {
    float xs0 = ldc(x, ((b * TIN_ + s) * N_ + n) * F_ + 0);
    float xs1 = ldc(x, ((b * TIN_ + s) * N_ + n) * F_ + 1);
#pragma unroll
    for (int d = 0; d < D_; ++d)
      acc[d] += sc[s] * (xs0 * wv[0][d] + xs1 * wv[1][d] + bvv[d]);
  }
  bf16* o = att_t + ((size_t)((b * 11 + (t - 1)) * N_ + n)) * C_ + h * D_;
#pragma unroll
  for (int d = 0; d < D_; ++d) o[d] = __float2bfloat16(acc[d] * inv);
}

// ---------------- spatial body (rank-2, head-split) ------------------------
template <typename TI>
__device__ __forceinline__ void spatial3_body(
    float2* xs, float (*M)[9], float (*Vw)[3][D_], float (*pt)[100][8],
    int tile, int ty, int b, int hg,
    const TI* x, const TI* Wq, const TI* Wk, const TI* Wv,
    const TI* bq, const TI* bk, const TI* bv, bf16* att_st) {
  int t = ty + 1;
  int tid = threadIdx.x;

  for (int m = tid; m < N_; m += 832)
    xs[m] = make_float2(ldc(x, ((b * TIN_ + t) * N_ + m) * F_ + 0),
                        ldc(x, ((b * TIN_ + t) * N_ + m) * F_ + 1));
  if (tid < 18) {
    int lh = tid / 9, e = tid % 9, a = e / 3, bb = e % 3;
    int h = hg * 2 + lh;
    float acc = 0.f;
    for (int d = 0; d < 8; ++d) {
      float qa = (a == 0) ? ldc(Wq, (h * 2 + 0) * 8 + d)
               : (a == 1) ? ldc(Wq, (h * 2 + 1) * 8 + d) : ldc(bq, h * 8 + d);
      float kb = (bb == 0) ? ldc(Wk, (h * 2 + 0) * 8 + d)
               : (bb == 1) ? ldc(Wk, (h * 2 + 1) * 8 + d) : ldc(bk, h * 8 + d);
      acc += qa * kb;
    }
    M[lh][e] = acc * SCALE * LOG2E;
  }
  if (tid >= 64 && tid < 64 + 48) {
    int e = tid - 64;
    int lh = e / 24, a = (e % 24) / 8, d = e % 8;
    int h = hg * 2 + lh;
    Vw[lh][a][d] = (a == 0) ? ldc(Wv, (h * 2 + 0) * 8 + d)
                 : (a == 1) ? ldc(Wv, (h * 2 + 1) * 8 + d) : ldc(bv, h * 8 + d);
  }
  __syncthreads();
  if (tid < 800) {
    int ms = tid / 100, nl = tid % 100;
    int n = tile * 100 + nl;
    float x0 = xs[n].x, x1 = xs[n].y;
    float A[2], Bc[2], Cc[2];
#pragma unroll
    for (int lh = 0; lh < 2; ++lh) {
      A[lh]  = M[lh][0] * x0 + M[lh][3] * x1 + M[lh][6];
      Bc[lh] = M[lh][1] * x0 + M[lh][4] * x1 + M[lh][7];
      Cc[lh] = M[lh][2] * x0 + M[lh][5] * x1 + M[lh][8];
    }
    float Sp[2] = {0, 0}, S0[2] = {0, 0}, S1[2] = {0, 0};
    for (int m = ms * 100; m < ms * 100 + 100; ++m) {
      float2 xm = xs[m];
#pragma unroll
      for (int lh = 0; lh < 2; ++lh) {
        float p = exp2_(A[lh] * xm.x + Bc[lh] * xm.y + Cc[lh]);
        Sp[lh] += p;
        S0[lh] += p * xm.x;
        S1[lh] += p * xm.y;
      }
    }
#pragma unroll
    for (int lh = 0; lh < 2; ++lh) {
      pt[ms][nl][lh * 3 + 0] = Sp[lh];
      pt[ms][nl][lh * 3 + 1] = S0[lh];
      pt[ms][nl][lh * 3 + 2] = S1[lh];
    }
  }
  __syncthreads();
  if (tid < 100) {
    int n = tile * 100 + tid;
    bf16* o = att_st + ((size_t)((b * 11 + ty) * N_ + n)) * C_;
#pragma unroll
    for (int lh = 0; lh < 2; ++lh) {
      int h = hg * 2 + lh;
      float Sp = 0.f, S0 = 0.f, S1 = 0.f;
#pragma unroll
      for (int ms = 0; ms < 8; ++ms) {
        Sp += pt[ms][tid][lh * 3 + 0];
        S0 += pt[ms][tid][lh * 3 + 1];
        S1 += pt[ms][tid][lh * 3 + 2];
      }
      float inv = 1.f / Sp;
#pragma unroll
      for (int d = 0; d < 8; ++d)
        o[h * 8 + d] = __float2bfloat16((S0 * Vw[lh][0][d] + S1 * Vw[lh][1][d] + Sp * Vw[lh][2][d]) * inv);
    }
  }
}

// ---------------- convx body, 4 units per block ----------------------------
// unit u handles one (tile,t,b); u_tid in [0,192); cw shared across units.
template <typename TI>
__device__ __forceinline__ void convx4_body(
    float (*tpw)[KW_][2], float (*cw)[KW_][48], unsigned short (*preS)[72],
    bool act, int u_tid, int tile, int t, int b,
    const TI* x, const TI* T,
    const TI* conv1_w, const TI* conv1_b,
    const TI* lwz, const TI* lwr, const TI* lwh,
    const TI* lbz, const TI* lbr, const TI* lbh,
    bf16* xfrag, int unit) {
  int wv = u_tid / 64, l = u_tid & 63;
  int cg = l >> 4, cl = l & 15;
  int rw = u_tid / 12, jl = u_tid % 12;

  if (act) {
    if (unit == 0) {
#pragma unroll 7
      for (int p = 0; p < 7; ++p) {
        int e = u_tid + p * 192;
        int f = e / (KW_ * 48), rem = e % (KW_ * 48), k = rem / 48, c = rem % 48;
        cw[f][k][c] = ldc(conv1_w, (c * F_ + f) * KW_ + k);
      }
    }
#pragma unroll 10
    for (int p = 0; p < 10; ++p) {
      int e = u_tid + p * 192;
      if (e < 64 * KW_ * 2) {
        int rr = e / (KW_ * 2), rem = e % (KW_ * 2), k = rem / 2, f = rem % 2;
        int n = tile * 64 + rr; if (n > 799) n = 799;
        int tau = t + k;
        float v;
        if (tau < TIN_) v = ldc(x, ((size_t)(b * TIN_ + tau) * N_ + n) * F_ + f);
        else if (tau < TIN_ + TP_) v = (f == 0) ? 0.f : ldc(T, (size_t)(b * TP_ + (tau - TIN_)) * N_ + n);
        else v = ldc(x, ((size_t)(b * TIN_ + 0) * N_ + n) * F_ + f);
        tpw[rr][k][f] = v;
      }
    }
    for (int e = u_tid; e < 64 * 24; e += 192)
      preS[e / 24][48 + e % 24] = 0;
  }
  __syncthreads();
  if (act) {
    int c0 = jl * 4;
    float acc[4][4];
#pragma unroll
    for (int qq = 0; qq < 4; ++qq)
#pragma unroll
      for (int m = 0; m < 4; ++m) acc[qq][m] = ldc(conv1_b, c0 + m);
#pragma unroll
    for (int f = 0; f < 2; ++f)
      for (int k = 0; k < KW_; ++k) {
        const float4 w4 = *(const float4*)&cw[f][k][c0];
        float wvv[4] = {w4.x, w4.y, w4.z, w4.w};
#pragma unroll
        for (int qq = 0; qq < 4; ++qq) {
          float tv = tpw[rw * 4 + qq][k][f];
#pragma unroll
          for (int m = 0; m < 4; ++m) acc[qq][m] += tv * wvv[m];
        }
      }
#pragma unroll
    for (int qq = 0; qq < 4; ++qq)
#pragma unroll
      for (int m = 0; m < 4; ++m)
        preS[rw * 4 + qq][c0 + m] = f2u(acc[qq][m]);
  }
  __syncthreads();
  if (act) {
#pragma unroll
    for (int q = 0; q < 3; ++q) {
      int nt = 3 * wv + q;
      int g = nt / 3;
      int jj = (nt - g * 3) * 16 + cl;
      const TI* wl = (g == 0) ? lwz : (g == 1) ? lwr : lwh;
      const TI* bl = (g == 0) ? lbz : (g == 1) ? lbr : lbh;
      s8b Bf0, Bf1;
#pragma unroll
      for (int j = 0; j < 8; ++j) {
        int k0 = cg * 8 + j;
        int k1 = 32 + cg * 8 + j;
        Bf0[j] = (short)f2u(ldc(wl, ((size_t)t * 96 + k0) * 48 + jj));
        Bf1[j] = (k1 < 48) ? (short)f2u(ldc(wl, ((size_t)t * 96 + k1) * 48 + jj)) : (short)0;
      }
#pragma unroll
      for (int mt = 0; mt < 4; ++mt) {
        int nbase = tile * 64 + mt * 16;
        if (nbase >= 800) continue;
        s8b A0 = *(const s8b*)&preS[mt * 16 + cl][cg * 8];
        s8b A1 = *(const s8b*)&preS[mt * 16 + cl][32 + cg * 8];
        f4 acc;
#pragma unroll
        for (int r = 0; r < 4; ++r)
          acc[r] = ldc(bl, ((size_t)t * N_ + (nbase + cg * 4 + r)) * C_ + jj);
        acc = __builtin_amdgcn_mfma_f32_16x16x32_bf16(A0, Bf0, acc, 0, 0, 0);
        acc = __builtin_amdgcn_mfma_f32_16x16x32_bf16(A1, Bf1, acc, 0, 0, 0);
        int grp = b * 50 + tile * 4 + mt;
        size_t idx = ((((size_t)grp * 21 + (11 + t)) * 9 + nt) * 64 + l) * 4;
        ushort4 u;
        u.x = f2u(acc[0]); u.y = f2u(acc[1]); u.z = f2u(acc[2]); u.w = f2u(acc[3]);
        *(ushort4*)((unsigned short*)xfrag + idx) = u;
      }
    }
  }
}

// ---------------- K1: merged spatial + temporal + pack + convx4 ------------
#define SP_BLKS 528
#define TMP_BLKS 127
#define PK_BLKS 233
#define CV_BLKS 65
#define TOT_BLKS 953   // prime
__global__ __launch_bounds__(832) void k_phase1(
    const void* x, const void* T,
    const void* Wq_t, const void* Wk_t, const void* Wv_t,
    const void* bq_t, const void* bk_t, const void* bv_t,
    const void* Wq_st, const void* Wk_st, const void* Wv_st,
    const void* bq_st, const void* bk_st, const void* bv_st,
    const void* conv1_w, const void* conv1_b,
    const void* xwz, const void* xwr, const void* xwh,
    const void* lwz, const void* lwr, const void* lwh,
    const void* lbz, const void* lbr, const void* lbh,
    bf16* att_t, bf16* att_st, bf16* xfrag, bf16* pwb) {
  __shared__ __align__(16) char smem[70912];
  int f32 = detect_f32(x);
  int lid = (int)(((long long)blockIdx.x * 389) % TOT_BLKS);
  if (lid < SP_BLKS) {
    auto xs = (float2*)smem;
    auto M  = (float(*)[9])(smem + 6400);
    auto Vw = (float(*)[3][D_])(smem + 6480);
    auto pt = (float(*)[100][8])(smem + 6720);
    int tile = lid % 8, ty = (lid / 8) % 11, zz = lid / 88;
    int b = zz / 3, hg = zz % 3;
    if (f32)
      spatial3_body<float>(xs, M, Vw, pt, tile, ty, b, hg,
                           (const float*)x, (const float*)Wq_st, (const float*)Wk_st,
                           (const float*)Wv_st, (const float*)bq_st, (const float*)bk_st,
                           (const float*)bv_st, att_st);
    else
      spatial3_body<bf16>(xs, M, Vw, pt, tile, ty, b, hg,
                          (const bf16*)x, (const bf16*)Wq_st, (const bf16*)Wk_st,
                          (const bf16*)Wv_st, (const bf16*)bq_st, (const bf16*)bk_st,
                          (const bf16*)bv_st, att_st);
  } else if (lid < SP_BLKS + TMP_BLKS) {
    int gid = (lid - SP_BLKS) * 832 + threadIdx.x;
    if (f32)
      temporal_body<float>(gid, (const float*)x, (const float*)Wq_t, (const float*)Wk_t,
                           (const float*)Wv_t, (const float*)bq_t, (const float*)bk_t,
                           (const float*)bv_t, att_t);
    else
      temporal_body<bf16>(gid, (const bf16*)x, (const bf16*)Wq_t, (const bf16*)Wk_t,
                          (const bf16*)Wv_t, (const bf16*)bq_t, (const bf16*)bk_t,
                          (const bf16*)bv_t, att_t);
  } else if (lid < SP_BLKS + TMP_BLKS + PK_BLKS) {
    int gid = (lid - SP_BLKS - TMP_BLKS) * 832 + threadIdx.x;
    if (f32)
      pack_body<float>(gid, (const float*)xwz, (const float*)xwr, (const float*)xwh,
                       (const float*)lwz, (const float*)lwr, (const float*)lwh, pwb);
    else
      pack_body<bf16>(gid, (const bf16*)xwz, (const bf16*)xwr, (const bf16*)xwh,
                      (const bf16*)lwz, (const bf16*)lwr, (const bf16*)lwh, pwb);
  } else {
    int cbase = (lid - SP_BLKS - TMP_BLKS - PK_BLKS) * 4;
    int tid = threadIdx.x;
    int unit = tid / 192;             // 0..3 active; 4 = idle wave
    bool act = unit < 4;
    int u_tid = tid - unit * 192;
    int cblk = cbase + (act ? unit : 0);
    int tile = cblk % 13, t = (cblk / 13) % 10, b = cblk / 130;
    int uu = act ? unit : 0;
    auto tpw  = (float(*)[KW_][2])(smem + uu * 7168);
    auto cw   = (float(*)[KW_][48])(smem + 4 * 7168);
    auto preS = (unsigned short(*)[72])(smem + 4 * 7168 + 5376 + uu * 9216);
    if (f32)
      convx4_body<float>(tpw, cw, preS, act, u_tid, tile, t, b,
                         (const float*)x, (const float*)T, (const float*)conv1_w,
                         (const float*)conv1_b, (const float*)lwz, (const float*)lwr,
                         (const float*)lwh, (const float*)lbz, (const float*)lbr,
                         (const float*)lbh, xfrag, act ? unit : -1);
    else
      convx4_body<bf16>(tpw, cw, preS, act, u_tid, tile, t, b,
                        (const bf16*)x, (const bf16*)T, (const bf16*)conv1_w,
                        (const bf16*)conv1_b, (const bf16*)lwz, (const bf16*)lwr,
                        (const bf16*)lwh, (const bf16*)lbz, (const bf16*)lbr,
                        (const bf16*)lbh, xfrag, act ? unit : -1);
  }
}

// ---------------- K2: projx (MFMA, unchanged math) -------------------------
template <typename TI>
__device__ __forceinline__ void projx2_body(
    unsigned short (*rawT)[72], unsigned short (*rawS)[72], unsigned short (*catS)[104],
    const bf16* att_t, const bf16* att_st,
    const TI* Wpt, const TI* bpt, const TI* Wps, const TI* bps,
    const TI* xwz, const TI* xwr, const TI* xwh,
    const TI* xbz, const TI* xbr, const TI* xbh,
    bf16* xfrag) {
  int tile = blockIdx.x, ty = blockIdx.y, b = blockIdx.z;
  int t = ty + 1;
  int tid = threadIdx.x;
  int wv = tid >> 6, l = tid & 63;
  int cg = l >> 4, cl = l & 15;

  for (int e = tid; e < 64 * 72; e += 192) {
    int rr = e / 72, c = e % 72;
    int n = tile * 64 + rr; if (n > 799) n = 799;
    size_t base = ((size_t)((b * 11 + ty) * N_ + n)) * C_;
    rawT[rr][c] = (c < 48) ? __bfloat16_as_ushort(att_t[base + c]) : (unsigned short)0;
    rawS[rr][c] = (c < 48) ? __bfloat16_as_ushort(att_st[base + c]) : (unsigned short)0;
  }
  __syncthreads();
#pragma unroll
  for (int q = 0; q < 2; ++q) {
    int nt = 2 * wv + q;
    int half = nt / 3;
    int ncol = (nt - half * 3) * 16 + cl;
    float bias = half ? ldc(bps, ncol) : ldc(bpt, ncol);
    s8b Bf0, Bf1;
#pragma unroll
    for (int j = 0; j < 8; ++j) {
      int k0 = cg * 8 + j;
      int k1 = 32 + cg * 8 + j;
      Bf0[j] = (short)f2u(half ? ldc(Wps, (size_t)k0 * 48 + ncol)
                               : ldc(Wpt, (size_t)k0 * 48 + ncol));
      Bf1[j] = (k1 < 48) ? (short)f2u(half ? ldc(Wps, (size_t)k1 * 48 + ncol)
                                           : ldc(Wpt, (size_t)k1 * 48 + ncol))
                         : (short)0;
    }
    unsigned short (*raw)[72] = half ? rawS : rawT;
#pragma unroll
    for (int mt = 0; mt < 4; ++mt) {
      s8b A0 = *(const s8b*)&raw[mt * 16 + cl][cg * 8];
      s8b A1 = *(const s8b*)&raw[mt * 16 + cl][32 + cg * 8];
      f4 acc = {bias, bias, bias, bias};
      acc = __builtin_amdgcn_mfma_f32_16x16x32_bf16(A0, Bf0, acc, 0, 0, 0);
      acc = __builtin_amdgcn_mfma_f32_16x16x32_bf16(A1, Bf1, acc, 0, 0, 0);
#pragma unroll
      for (int r = 0; r < 4; ++r)
        catS[mt * 16 + cg * 4 + r][nt * 16 + cl] = f2u(acc[r]);
    }
  }
  __syncthreads();
#pragma unroll
  for (int q = 0; q < 3; ++q) {
    int nt = 3 * wv + q;
    int g = nt / 3;
    int jj = (nt - g * 3) * 16 + cl;
    const TI* wx = (g == 0) ? xwz : (g == 1) ? xwr : xwh;
    const TI* bx = (g == 0) ? xbz : (g == 1) ? xbr : xbh;
    s8b Bf[3];
#pragma unroll
    for (int c = 0; c < 3; ++c)
#pragma unroll
      for (int j = 0; j < 8; ++j) {
        int k = c * 32 + cg * 8 + j;
        Bf[c][j] = (short)f2u(ldc(wx, ((size_t)t * 144 + k) * 48 + jj));
      }
#pragma unroll
    for (int mt = 0; mt < 4; ++mt) {
      int nbase = tile * 64 + mt * 16;
      if (nbase >= 800) continue;
      s8b A0 = *(const s8b*)&catS[mt * 16 + cl][cg * 8];
      s8b A1 = *(const s8b*)&catS[mt * 16 + cl][32 + cg * 8];
      s8b A2 = *(const s8b*)&catS[mt * 16 + cl][64 + cg * 8];
      f4 acc;
#pragma unroll
      for (int r = 0; r < 4; ++r)
        acc[r] = ldc(bx, ((size_t)t * N_ + (nbase + cg * 4 + r)) * C_ + jj);
      acc = __builtin_amdgcn_mfma_f32_16x16x32_bf16(A0, Bf[0], acc, 0, 0, 0);
      acc = __builtin_amdgcn_mfma_f32_16x16x32_bf16(A1, Bf[1], acc, 0, 0, 0);
      acc = __builtin_amdgcn_mfma_f32_16x16x32_bf16(A2, Bf[2], acc, 0, 0, 0);
      int grp = b * 50 + tile * 4 + mt;
      size_t idx = ((((size_t)grp * 21 + ty) * 9 + nt) * 64 + l) * 4;
      ushort4 u;
      u.x = f2u(acc[0]); u.y = f2u(acc[1]); u.z = f2u(acc[2]); u.w = f2u(acc[3]);
      *(ushort4*)((unsigned short*)xfrag + idx) = u;
    }
  }
}
__global__ __launch_bounds__(192) void k_projx(
    const bf16* att_t, const bf16* att_st,
    const void* Wpt, const void* bpt, const void* Wps, const void* bps,
    const void* xwz, const void* xwr, const void* xwh,
    const void* xbz, const void* xbr, const void* xbh,
    const void* x, bf16* xfrag) {
  __shared__ __align__(16) char smem[31744];
  int f32 = detect_f32(x);
  auto rawT = (unsigned short(*)[72])smem;
  auto rawS = (unsigned short(*)[72])(smem + 9216);
  auto catS = (unsigned short(*)[104])(smem + 18432);
  if (f32)
    projx2_body<float>(rawT, rawS, catS, att_t, att_st,
                       (const float*)Wpt, (const float*)bpt, (const float*)Wps,
                       (const float*)bps, (const float*)xwz, (const float*)xwr,
                       (const float*)xwh, (const float*)xbz, (const float*)xbr,
                       (const float*)xbh, xfrag);
  else
    projx2_body<bf16>(rawT, rawS, catS, att_t, att_st,
                      (const bf16*)Wpt, (const bf16*)bpt, (const bf16*)Wps,
                      (const bf16*)bps, (const bf16*)xwz, (const bf16*)xwr,
                      (const bf16*)xwh, (const bf16*)xbz, (const bf16*)xbr,
                      (const bf16*)xbh, xfrag);
}

// ---------------- K3: MFMA GRU v11 — DMA pipeline, wait-shadowed ----------
template <typename TI, typename TO>
__device__ __forceinline__ void gru11_body(
    unsigned short (*wbuf)[9216], unsigned short (*xbuf)[2560],
    unsigned short* hT, unsigned short* rhT,
    const unsigned short* xfrag, const unsigned short* pwb,
    const TI* Wout, const TI* bout, TO* out) {
  int l = threadIdx.x;          // 64
  int cg = l >> 4, cl = l & 15;
  int blk = blockIdx.x;
  int b = blk / 50;
  int n0 = (blk % 50) * 16;

  for (int e = l; e < 1152; e += 64) { hT[e] = 0; rhT[e] = 0; }
  float bo = ldc(bout, 0);
  s8b WoB0, WoB1;   // Wout B-fragment (col 0 only)
#pragma unroll
  for (int j = 0; j < 8; ++j) {
    int k0 = cg * 8 + j;
    int k1 = 32 + cg * 8 + j;
    WoB0[j] = (cl == 0) ? (short)f2u(ldc(Wout, k0)) : (short)0;
    WoB1[j] = (cl == 0 && k1 < 48) ? (short)f2u(ldc(Wout, k1)) : (short)0;
  }
  float ho[3][4];
#pragma unroll
  for (int nt = 0; nt < 3; ++nt)
#pragma unroll
    for (int r = 0; r < 4; ++r) ho[nt][r] = 0.f;

  const unsigned short* xg = xfrag + (size_t)blk * 48384;
#pragma unroll
  for (int i = 0; i < 18; ++i) gll16(pwb + i * 512 + l * 8, &wbuf[0][i * 512]);
#pragma unroll
  for (int i = 0; i < 5; ++i) gll16(xg + i * 512 + l * 8, &xbuf[0][i * 512]);
  asm volatile("" ::: "memory");

  for (int step = 0; step < 21; ++step) {
    int cur = step & 1;
    // --- DMA-independent work first: hT A-frags + decoder output (shadows wait)
    s8b hA0 = *(const s8b*)&hT[cl * 72 + cg * 8];
    s8b hA1 = *(const s8b*)&hT[cl * 72 + 32 + cg * 8];
    if (step >= 12) {
      f4 oacc = {bo, bo, bo, bo};
      oacc = __builtin_amdgcn_mfma_f32_16x16x32_bf16(hA0, WoB0, oacc, 0, 0, 0);
      oacc = __builtin_amdgcn_mfma_f32_16x16x32_bf16(hA1, WoB1, oacc, 0, 0, 0);
      if (cl == 0) {
        int t = step - 12;
#pragma unroll
        for (int r = 0; r < 4; ++r)
          sto(out, ((size_t)b * TP_ + t) * N_ + n0 + cg * 4 + r, oacc[r]);
      }
    }
    asm volatile("s_waitcnt vmcnt(0)" ::: "memory");
    s8b Wz[3][2], Wr[3][2], Wh[3][2];
    const unsigned short* wb = wbuf[cur];
#pragma unroll
    for (int nt = 0; nt < 3; ++nt)
#pragma unroll
      for (int c = 0; c < 2; ++c) {
        Wz[nt][c] = *(const s8b*)&wb[0 * 3072 + nt * 1024 + c * 512 + l * 8];
        Wr[nt][c] = *(const s8b*)&wb[1 * 3072 + nt * 1024 + c * 512 + l * 8];
        Wh[nt][c] = *(const s8b*)&wb[2 * 3072 + nt * 1024 + c * 512 + l * 8];
      }
    ushort4 cx[9];
#pragma unroll
    for (int gn = 0; gn < 9; ++gn)
      cx[gn] = *(const ushort4*)&xbuf[cur][gn * 256 + l * 4];
    if (step < 20) {
      const unsigned short* wsn = pwb + (size_t)(step + 1) * 9216;
#pragma unroll
      for (int i = 0; i < 18; ++i) gll16(wsn + i * 512 + l * 8, &wbuf[cur ^ 1][i * 512]);
      const unsigned short* xsn = xg + (size_t)(step + 1) * 2304;
#pragma unroll
      for (int i = 0; i < 5; ++i) gll16(xsn + i * 512 + l * 8, &xbuf[cur ^ 1][i * 512]);
    }
    f4 az[3], ar[3];
#pragma unroll
    for (int nt = 0; nt < 3; ++nt) {
      f4 cz = {bfu(cx[nt].x), bfu(cx[nt].y), bfu(cx[nt].z), bfu(cx[nt].w)};
      cz = __builtin_amdgcn_mfma_f32_16x16x32_bf16(hA0, Wz[nt][0], cz, 0, 0, 0);
      cz = __builtin_amdgcn_mfma_f32_16x16x32_bf16(hA1, Wz[nt][1], cz, 0, 0, 0);
      az[nt] = cz;
      f4 cr = {bfu(cx[3 + nt].x), bfu(cx[3 + nt].y), bfu(cx[3 + nt].z), bfu(cx[3 + nt].w)};
      cr = __builtin_amdgcn_mfma_f32_16x16x32_bf16(hA0, Wr[nt][0], cr, 0, 0, 0);
      cr = __builtin_amdgcn_mfma_f32_16x16x32_bf16(hA1, Wr[nt][1], cr, 0, 0, 0);
      ar[nt] = cr;
    }
    float z[3][4];
#pragma unroll
    for (int nt = 0; nt < 3; ++nt)
#pragma unroll
      for (int r = 0; r < 4; ++r) {
        z[nt][r] = sigm(az[nt][r]);
        float rv = sigm(ar[nt][r]) * ho[nt][r];
        rhT[(cg * 4 + r) * 72 + nt * 16 + cl] = f2u(rv);
      }
    asm volatile("" ::: "memory");
    s8b rA0 = *(const s8b*)&rhT[cl * 72 + cg * 8];
    s8b rA1 = *(const s8b*)&rhT[cl * 72 + 32 + cg * 8];
    f4 ah[3];
#pragma unroll
    for (int nt = 0; nt < 3; ++nt) {
      f4 ch = {bfu(cx[6 + nt].x), bfu(cx[6 + nt].y), bfu(cx[6 + nt].z), bfu(cx[6 + nt].w)};
      ch = __builtin_amdgcn_mfma_f32_16x16x32_bf16(rA0, Wh[nt][0], ch, 0, 0, 0);
      ch = __builtin_amdgcn_mfma_f32_16x16x32_bf16(rA1, Wh[nt][1], ch, 0, 0, 0);
      ah[nt] = ch;
    }
#pragma unroll
    for (int nt = 0; nt < 3; ++nt)
#pragma unroll
      for (int r = 0; r < 4; ++r) {
        float hn = (1.f - z[nt][r]) * ho[nt][r] + z[nt][r] * tanh_(ah[nt][r]);
        ho[nt][r] = hn;
        hT[(cg * 4 + r) * 72 + nt * 16 + cl] = f2u(hn);
      }
    asm volatile("" ::: "memory");
  }
  // epilogue: output t=9 from final h
  {
    s8b hA0 = *(const s8b*)&hT[cl * 72 + cg * 8];
    s8b hA1 = *(const s8b*)&hT[cl * 72 + 32 + cg * 8];
    f4 oacc = {bo, bo, bo, bo};
    oacc = __builtin_amdgcn_mfma_f32_16x16x32_bf16(hA0, WoB0, oacc, 0, 0, 0);
    oacc = __builtin_amdgcn_mfma_f32_16x16x32_bf16(hA1, WoB1, oacc, 0, 0, 0);
    if (cl == 0) {
#pragma unroll
      for (int r = 0; r < 4; ++r)
        sto(out, ((size_t)b * TP_ + 9) * N_ + n0 + cg * 4 + r, oacc[r]);
    }
  }
}
__global__ __launch_bounds__(64) void k_gru11(
    const void* xin, const bf16* xfrag, const bf16* pwb,
    const void* Wout, const void* bout, void* out) {
  __shared__ alignas(16) unsigned short wbuf[2][9216];
  __shared__ alignas(16) unsigned short xbuf[2][2560];
  __shared__ alignas(16) unsigned short hT[1152];
  __shared__ alignas(16) unsigned short rhT[1152];
  int f32 = detect_f32(xin);
  if (f32)
    gru11_body<float, float>(wbuf, xbuf, hT, rhT,
                             (const unsigned short*)xfrag, (const unsigned short*)pwb,
                             (const float*)Wout, (const float*)bout, (float*)out);
  else
    gru11_body<bf16, bf16>(wbuf, xbuf, hT, rhT,
                           (const unsigned short*)xfrag, (const unsigned short*)pwb,
                           (const bf16*)Wout, (const bf16*)bout, (bf16*)out);
}

// ---------------------------------------------------------------------------
extern "C" void kernel_launch(void* const* d_in, const int* in_sizes, int n_in,
                              void* d_out, int out_size, void* d_ws, size_t ws_size,
                              hipStream_t stream) {
  (void)in_sizes; (void)n_in; (void)out_size; (void)ws_size;
  const void* x       = d_in[0];
  const void* T       = d_in[1];
  const void* Wq_t    = d_in[3];
  const void* Wk_t    = d_in[4];
  const void* Wv_t    = d_in[5];
  const void* Wq_st   = d_in[6];
  const void* Wk_st   = d_in[7];
  const void* Wv_st   = d_in[8];
  const void* bq_t    = d_in[9];
  const void* bk_t    = d_in[10];
  const void* bv_t    = d_in[11];
  const void* bq_st   = d_in[12];
  const void* bk_st   = d_in[13];
  const void* bv_st   = d_in[14];
  const void* conv1_w = d_in[15];
  const void* conv1_b = d_in[16];
  const void* Wproj_t = d_in[17];
  const void* bproj_t = d_in[18];
  const void* Wproj_st= d_in[19];
  const void* bproj_st= d_in[20];
  const void* xhr_wz  = d_in[21];
  const void* xhr_wr  = d_in[22];
  const void* xhr_wh  = d_in[23];
  const void* xhr_bz  = d_in[24];
  const void* xhr_br  = d_in[25];
  const void* xhr_bh  = d_in[26];
  const void* last_wz = d_in[27];
  const void* last_wr = d_in[28];
  const void* last_wh = d_in[29];
  const void* last_bz = d_in[30];
  const void* last_br = d_in[31];
  const void* last_bh = d_in[32];
  const void* Wout    = d_in[33];
  const void* bout    = d_in[34];

  // ws layout (~13.2 MB; proven safe earlier)
  char* wsb = (char*)d_ws;
  bf16* att_t  = (bf16*)(wsb + 256);                     // 2*11*800*48
  bf16* att_st = att_t + (size_t)2 * 11 * 800 * 48;
  bf16* xfrag  = att_st + (size_t)2 * 11 * 800 * 48;     // 100*21*9*64*4 elems
  bf16* pwb    = xfrag + (size_t)100 * 21 * 9 * 64 * 4;  // 21*9216 (compact)

  k_phase1<<<TOT_BLKS, 832, 0, stream>>>(
      x, T, Wq_t, Wk_t, Wv_t, bq_t, bk_t, bv_t,
      Wq_st, Wk_st, Wv_st, bq_st, bk_st, bv_st,
      conv1_w, conv1_b, xhr_wz, xhr_wr, xhr_wh,
      last_wz, last_wr, last_wh, last_bz, last_br, last_bh,
      att_t, att_st, xfrag, pwb);
  k_projx<<<dim3(13, 11, 2), 192, 0, stream>>>(
      att_t, att_st, Wproj_t, bproj_t, Wproj_st, bproj_st,
      xhr_wz, xhr_wr, xhr_wh, xhr_bz, xhr_br, xhr_bh, x, xfrag);
  k_gru11<<<100, 64, 0, stream>>>(
      x, xfrag, pwb, Wout, bout, d_out);
}

// Round 17
// 119.895 us; speedup vs baseline: 1.0876x; 1.0876x over previous
//
#include <hip/hip_runtime.h>
#include <hip/hip_bf16.h>

typedef __hip_bfloat16 bf16;
typedef __attribute__((ext_vector_type(8))) short s8b;   // 8 bf16 (4 VGPR)
typedef __attribute__((ext_vector_type(4))) float f4;    // MFMA C/D

#define B_ 2
#define TIN_ 12
#define N_ 800
#define F_ 2
#define H_ 6
#define D_ 8
#define C_ 48
#define TP_ 10
#define KW_ 14
#define SCALE 0.35355339059327373f  // 1/sqrt(8)
#define LOG2E 1.4426950408889634f

__device__ __forceinline__ float sigm(float x) { return 1.0f / (1.0f + __expf(-x)); }
__device__ __forceinline__ float tanh_(float x) {
  float e = __expf(-2.0f * x);
  return 2.0f / (1.0f + e) - 1.0f;
}
__device__ __forceinline__ float exp2_(float x) { return __builtin_amdgcn_exp2f(x); }
__device__ __forceinline__ float bfu(unsigned short u) {
  return __uint_as_float((unsigned)u << 16);
}
__device__ __forceinline__ unsigned short f2u(float v) {
  return __bfloat16_as_ushort(__float2bfloat16(v));
}
__device__ __forceinline__ float ldc(const float* p, size_t i) { return p[i]; }
__device__ __forceinline__ float ldc(const bf16* p, size_t i) { return __bfloat162float(p[i]); }
__device__ __forceinline__ void sto(float* p, size_t i, float v) { p[i] = v; }
__device__ __forceinline__ void sto(bf16* p, size_t i, float v) { p[i] = __float2bfloat16(v); }
__device__ __forceinline__ void gll16(const void* g, void* l) {
  __builtin_amdgcn_global_load_lds(
      (__attribute__((address_space(1))) void*)(g),
      (__attribute__((address_space(3))) void*)(l), 16, 0, 0);
}
// per-wave dtype detection: f32 data -> low bf16 halves have wild exponents
__device__ __forceinline__ int detect_f32(const void* xv) {
  const unsigned int* xw = (const unsigned int*)xv;
  unsigned int w = xw[threadIdx.x & 63];
  int e = (w >> 7) & 0xFF;
  int bad = ((e >= 1 && e < 96) || (e > 150)) ? 1 : 0;
  unsigned long long m = __ballot(bad);
  return (__popcll(m) >= 16) ? 1 : 0;
}

// ---------------- pack body: compact MFMA B-fragments ----------------------
template <typename TI>
__device__ __forceinline__ void pack_body(
    int gid, const TI* xwz, const TI* xwr, const TI* xwh,
    const TI* lwz, const TI* lwr, const TI* lwh, bf16* pwb) {
  const int total = 21 * 9216;
  if (gid >= total) return;
  int step = gid / 9216, r = gid % 9216;
  int g = r / 3072;  r %= 3072;
  int nt = r / 1024; r %= 1024;
  int c = r / 512;   r %= 512;
  int lane = r / 8, j = r % 8;
  int k = 32 * c + (lane >> 4) * 8 + j;
  int n = nt * 16 + (lane & 15);
  float v = 0.f;
  if (k < 48) {
    if (step < 11) {
      int t = step + 1;
      const TI* w = (g == 0) ? xwz : (g == 1) ? xwr : xwh;
      v = ldc(w, ((size_t)t * 144 + 96 + k) * 48 + n);
    } else {
      int t = step - 11;
      const TI* w = (g == 0) ? lwz : (g == 1) ? lwr : lwh;
      v = ldc(w, ((size_t)t * 96 + 48 + k) * 48 + n);
    }
  }
  pwb[gid] = __float2bfloat16(v);
}

// ---------------- temporal body (per-element gid) --------------------------
template <typename TI>
__device__ __forceinline__ void temporal_body(
    int gid, const TI* x, const TI* Wq, const TI* Wk, const TI* Wv,
    const TI* bq, const TI* bk, const TI* bv, bf16* att_t) {
  const int total = B_ * (TIN_ - 1) * H_ * N_;
  if (gid >= total) return;
  int n = gid % N_;
  int r = gid / N_;
  int h = r % H_;  r /= H_;
  int t = (r % (TIN_ - 1)) + 1;
  int b = r / (TIN_ - 1);

  float wq[F_][D_], wk[F_][D_], wv[F_][D_], bqv[D_], bkv[D_], bvv[D_];
#pragma unroll
  for (int f = 0; f < F_; ++f)
#pragma unroll
    for (int d = 0; d < D_; ++d) {
      wq[f][d] = ldc(Wq, (h * F_ + f) * D_ + d);
      wk[f][d] = ldc(Wk, (h * F_ + f) * D_ + d);
      wv[f][d] = ldc(Wv, (h * F_ + f) * D_ + d);
    }
#pragma unroll
  for (int d = 0; d < D_; ++d) {
    bqv[d] = ldc(bq, h * D_ + d);
    bkv[d] = ldc(bk, h * D_ + d);
    bvv[d] = ldc(bv, h * D_ + d);
  }
  float xt0 = ldc(x, ((b * TIN_ + t) * N_ + n) * F_ + 0);
  float xt1 = ldc(x, ((b * TIN_ + t) * N_ + n) * F_ + 1);
  float q[D_];
#pragma unroll
  for (int d = 0; d < D_; ++d) q[d] = xt0 * wq[0][d] + xt1 * wq[1][d] + bqv[d];

  float sc[TIN_];
  float mx = -1e30f;
#pragma unroll
  for (int s = 0; s < TIN_; ++s) {
    float xs0 = ldc(x, ((b * TIN_ + s) * N_ + n) * F_ + 0);
    float xs1 = ldc(x, ((b * TIN_ + s) * N_ + n) * F_ + 1);
    float dot = 0.f;
#pragma unroll
    for (int d = 0; d < D_; ++d)
      dot += q[d] * (xs0 * wk[0][d] + xs1 * wk[1][d] + bkv[d]);
    dot *= SCALE;
    sc[s] = (s <= t) ? dot : -1e30f;
    mx = fmaxf(mx, sc[s]);
  }
  float sum = 0.f;
#pragma unroll
  for (int s = 0; s < TIN_; ++s) {
    float p = __expf(sc[s] - mx);
    sc[s] = p;
    sum += p;
  }
  float inv = 1.0f / sum;
  float acc[D_];
#pragma unroll
  for (int d = 0; d < D_; ++d) acc[d] = 0.f;
#pragma unroll
  for (int s = 0; s < TIN_; ++s) {
    float xs0 = ldc(x, ((b * TIN_ + s) * N_ + n) * F_ + 0);
    float xs1 = ldc(x, ((b * TIN_ + s) * N_ + n) * F_ + 1);
#pragma unroll
    for (int d = 0; d < D_; ++d)
      acc[d] += sc[s] * (xs0 * wv[0][d] + xs1 * wv[1][d] + bvv[d]);
  }
  bf16* o = att_t + ((size_t)((b * 11 + (t - 1)) * N_ + n)) * C_ + h * D_;
#pragma unroll
  for (int d = 0; d < D_; ++d) o[d] = __float2bfloat16(acc[d] * inv);
}

// ---------------- spatial4: rank-2, head-split, shfl-reduced ---------------
// 800 workers: row = tid>>3 (0..99), ms = tid&7 (m-chunk). Partials for a
// row live in 8 consecutive lanes of ONE wave -> 3x shfl_xor, no pt[] LDS.
template <typename TI>
__device__ __forceinline__ void spatial4_body(
    float2* xs, float (*M)[9], float (*Vw)[3][D_],
    int tile, int ty, int b, int hg,
    const TI* x, const TI* Wq, const TI* Wk, const TI* Wv,
    const TI* bq, const TI* bk, const TI* bv, bf16* att_st) {
  int t = ty + 1;
  int tid = threadIdx.x;

  for (int m = tid; m < N_; m += 832)
    xs[m] = make_float2(ldc(x, ((b * TIN_ + t) * N_ + m) * F_ + 0),
                        ldc(x, ((b * TIN_ + t) * N_ + m) * F_ + 1));
  if (tid < 18) {
    int lh = tid / 9, e = tid % 9, a = e / 3, bb = e % 3;
    int h = hg * 2 + lh;
    float acc = 0.f;
    for (int d = 0; d < 8; ++d) {
      float qa = (a == 0) ? ldc(Wq, (h * 2 + 0) * 8 + d)
               : (a == 1) ? ldc(Wq, (h * 2 + 1) * 8 + d) : ldc(bq, h * 8 + d);
      float kb = (bb == 0) ? ldc(Wk, (h * 2 + 0) * 8 + d)
               : (bb == 1) ? ldc(Wk, (h * 2 + 1) * 8 + d) : ldc(bk, h * 8 + d);
      acc += qa * kb;
    }
    M[lh][e] = acc * SCALE * LOG2E;
  }
  if (tid >= 64 && tid < 64 + 48) {
    int e = tid - 64;
    int lh = e / 24, a = (e % 24) / 8, d = e % 8;
    int h = hg * 2 + lh;
    Vw[lh][a][d] = (a == 0) ? ldc(Wv, (h * 2 + 0) * 8 + d)
                 : (a == 1) ? ldc(Wv, (h * 2 + 1) * 8 + d) : ldc(bv, h * 8 + d);
  }
  __syncthreads();
  if (tid < 800) {
    int row = tid >> 3, ms = tid & 7;
    int n = tile * 100 + row;
    float x0 = xs[n].x, x1 = xs[n].y;
    float A[2], Bc[2], Cc[2];
#pragma unroll
    for (int lh = 0; lh < 2; ++lh) {
      A[lh]  = M[lh][0] * x0 + M[lh][3] * x1 + M[lh][6];
      Bc[lh] = M[lh][1] * x0 + M[lh][4] * x1 + M[lh][7];
      Cc[lh] = M[lh][2] * x0 + M[lh][5] * x1 + M[lh][8];
    }
    float Sp[2] = {0, 0}, S0[2] = {0, 0}, S1[2] = {0, 0};
    for (int m = ms * 100; m < ms * 100 + 100; ++m) {
      float2 xm = xs[m];
#pragma unroll
      for (int lh = 0; lh < 2; ++lh) {
        float p = exp2_(A[lh] * xm.x + Bc[lh] * xm.y + Cc[lh]);
        Sp[lh] += p;
        S0[lh] += p * xm.x;
        S1[lh] += p * xm.y;
      }
    }
#pragma unroll
    for (int lh = 0; lh < 2; ++lh) {
#pragma unroll
      for (int off = 1; off < 8; off <<= 1) {
        Sp[lh] += __shfl_xor(Sp[lh], off);
        S0[lh] += __shfl_xor(S0[lh], off);
        S1[lh] += __shfl_xor(S1[lh], off);
      }
    }
    if (ms == 0) {
      bf16* o = att_st + ((size_t)((b * 11 + ty) * N_ + n)) * C_;
#pragma unroll
      for (int lh = 0; lh < 2; ++lh) {
        int h = hg * 2 + lh;
        float inv = 1.f / Sp[lh];
#pragma unroll
        for (int d = 0; d < 8; ++d)
          o[h * 8 + d] = __float2bfloat16(
              (S0[lh] * Vw[lh][0][d] + S1[lh] * Vw[lh][1][d] + Sp[lh] * Vw[lh][2][d]) * inv);
      }
    }
  }
}

// ---------------- K1: spatial4 + temporal + pack (LDS = 6.9 KB) ------------
#define SP_BLKS 528
#define TMP_BLKS 127
#define PK_BLKS 233
__global__ __launch_bounds__(832) void k_phase1(
    const void* x,
    const void* Wq_t, const void* Wk_t, const void* Wv_t,
    const void* bq_t, const void* bk_t, const void* bv_t,
    const void* Wq_st, const void* Wk_st, const void* Wv_st,
    const void* bq_st, const void* bk_st, const void* bv_st,
    const void* xwz, const void* xwr, const void* xwh,
    const void* lwz, const void* lwr, const void* lwh,
    bf16* att_t, bf16* att_st, bf16* pwb) {
  __shared__ float2 xs[N_];
  __shared__ float M[2][9];
  __shared__ float Vw[2][3][D_];
  int f32 = detect_f32(x);
  int bx = blockIdx.x;
  if (bx < SP_BLKS) {
    int tile = bx % 8, ty = (bx / 8) % 11, zz = bx / 88;
    int b = zz / 3, hg = zz % 3;
    if (f32)
      spatial4_body<float>(xs, M, Vw, tile, ty, b, hg,
                           (const float*)x, (const float*)Wq_st, (const float*)Wk_st,
                           (const float*)Wv_st, (const float*)bq_st, (const float*)bk_st,
                           (const float*)bv_st, att_st);
    else
      spatial4_body<bf16>(xs, M, Vw, tile, ty, b, hg,
                          (const bf16*)x, (const bf16*)Wq_st, (const bf16*)Wk_st,
                          (const bf16*)Wv_st, (const bf16*)bq_st, (const bf16*)bk_st,
                          (const bf16*)bv_st, att_st);
  } else if (bx < SP_BLKS + TMP_BLKS) {
    int gid = (bx - SP_BLKS) * 832 + threadIdx.x;
    if (f32)
      temporal_body<float>(gid, (const float*)x, (const float*)Wq_t, (const float*)Wk_t,
                           (const float*)Wv_t, (const float*)bq_t, (const float*)bk_t,
                           (const float*)bv_t, att_t);
    else
      temporal_body<bf16>(gid, (const bf16*)x, (const bf16*)Wq_t, (const bf16*)Wk_t,
                          (const bf16*)Wv_t, (const bf16*)bq_t, (const bf16*)bk_t,
                          (const bf16*)bv_t, att_t);
  } else {
    int gid = (bx - SP_BLKS - TMP_BLKS) * 832 + threadIdx.x;
    if (f32)
      pack_body<float>(gid, (const float*)xwz, (const float*)xwr, (const float*)xwh,
                       (const float*)lwz, (const float*)lwr, (const float*)lwh, pwb);
    else
      pack_body<bf16>(gid, (const bf16*)xwz, (const bf16*)xwr, (const bf16*)xwh,
                      (const bf16*)lwz, (const bf16*)lwr, (const bf16*)lwh, pwb);
  }
}

// ---------------- projx body (MFMA, unchanged math) ------------------------
template <typename TI>
__device__ __forceinline__ void projx2_body(
    unsigned short (*rawT)[72], unsigned short (*rawS)[72], unsigned short (*catS)[104],
    int tile, int ty, int b,
    const bf16* att_t, const bf16* att_st,
    const TI* Wpt, const TI* bpt, const TI* Wps, const TI* bps,
    const TI* xwz, const TI* xwr, const TI* xwh,
    const TI* xbz, const TI* xbr, const TI* xbh,
    bf16* xfrag) {
  int t = ty + 1;
  int tid = threadIdx.x;
  int wv = tid >> 6, l = tid & 63;
  int cg = l >> 4, cl = l & 15;

  for (int e = tid; e < 64 * 72; e += 192) {
    int rr = e / 72, c = e % 72;
    int n = tile * 64 + rr; if (n > 799) n = 799;
    size_t base = ((size_t)((b * 11 + ty) * N_ + n)) * C_;
    rawT[rr][c] = (c < 48) ? __bfloat16_as_ushort(att_t[base + c]) : (unsigned short)0;
    rawS[rr][c] = (c < 48) ? __bfloat16_as_ushort(att_st[base + c]) : (unsigned short)0;
  }
  __syncthreads();
#pragma unroll
  for (int q = 0; q < 2; ++q) {
    int nt = 2 * wv + q;
    int half = nt / 3;
    int ncol = (nt - half * 3) * 16 + cl;
    float bias = half ? ldc(bps, ncol) : ldc(bpt, ncol);
    s8b Bf0, Bf1;
#pragma unroll
    for (int j = 0; j < 8; ++j) {
      int k0 = cg * 8 + j;
      int k1 = 32 + cg * 8 + j;
      Bf0[j] = (short)f2u(half ? ldc(Wps, (size_t)k0 * 48 + ncol)
                               : ldc(Wpt, (size_t)k0 * 48 + ncol));
      Bf1[j] = (k1 < 48) ? (short)f2u(half ? ldc(Wps, (size_t)k1 * 48 + ncol)
                                           : ldc(Wpt, (size_t)k1 * 48 + ncol))
                         : (short)0;
    }
    unsigned short (*raw)[72] = half ? rawS : rawT;
#pragma unroll
    for (int mt = 0; mt < 4; ++mt) {
      s8b A0 = *(const s8b*)&raw[mt * 16 + cl][cg * 8];
      s8b A1 = *(const s8b*)&raw[mt * 16 + cl][32 + cg * 8];
      f4 acc = {bias, bias, bias, bias};
      acc = __builtin_amdgcn_mfma_f32_16x16x32_bf16(A0, Bf0, acc, 0, 0, 0);
      acc = __builtin_amdgcn_mfma_f32_16x16x32_bf16(A1, Bf1, acc, 0, 0, 0);
#pragma unroll
      for (int r = 0; r < 4; ++r)
        catS[mt * 16 + cg * 4 + r][nt * 16 + cl] = f2u(acc[r]);
    }
  }
  __syncthreads();
#pragma unroll
  for (int q = 0; q < 3; ++q) {
    int nt = 3 * wv + q;
    int g = nt / 3;
    int jj = (nt - g * 3) * 16 + cl;
    const TI* wx = (g == 0) ? xwz : (g == 1) ? xwr : xwh;
    const TI* bx = (g == 0) ? xbz : (g == 1) ? xbr : xbh;
    s8b Bf[3];
#pragma unroll
    for (int c = 0; c < 3; ++c)
#pragma unroll
      for (int j = 0; j < 8; ++j) {
        int k = c * 32 + cg * 8 + j;
        Bf[c][j] = (short)f2u(ldc(wx, ((size_t)t * 144 + k) * 48 + jj));
      }
#pragma unroll
    for (int mt = 0; mt < 4; ++mt) {
      int nbase = tile * 64 + mt * 16;
      if (nbase >= 800) continue;
      s8b A0 = *(const s8b*)&catS[mt * 16 + cl][cg * 8];
      s8b A1 = *(const s8b*)&catS[mt * 16 + cl][32 + cg * 8];
      s8b A2 = *(const s8b*)&catS[mt * 16 + cl][64 + cg * 8];
      f4 acc;
#pragma unroll
      for (int r = 0; r < 4; ++r)
        acc[r] = ldc(bx, ((size_t)t * N_ + (nbase + cg * 4 + r)) * C_ + jj);
      acc = __builtin_amdgcn_mfma_f32_16x16x32_bf16(A0, Bf[0], acc, 0, 0, 0);
      acc = __builtin_amdgcn_mfma_f32_16x16x32_bf16(A1, Bf[1], acc, 0, 0, 0);
      acc = __builtin_amdgcn_mfma_f32_16x16x32_bf16(A2, Bf[2], acc, 0, 0, 0);
      int grp = b * 50 + tile * 4 + mt;
      size_t idx = ((((size_t)grp * 21 + ty) * 9 + nt) * 64 + l) * 4;
      ushort4 u;
      u.x = f2u(acc[0]); u.y = f2u(acc[1]); u.z = f2u(acc[2]); u.w = f2u(acc[3]);
      *(ushort4*)((unsigned short*)xfrag + idx) = u;
    }
  }
}

// ---------------- convx body (192 threads, all active) ---------------------
template <typename TI>
__device__ __forceinline__ void convx5_body(
    float (*tpw)[KW_][2], float (*cw)[KW_][48], unsigned short (*preS)[72],
    int tile, int t, int b,
    const TI* x, const TI* T,
    const TI* conv1_w, const TI* conv1_b,
    const TI* lwz, const TI* lwr, const TI* lwh,
    const TI* lbz, const TI* lbr, const TI* lbh,
    bf16* xfrag) {
  int tid = threadIdx.x;
  int wv = tid >> 6, l = tid & 63;
  int cg = l >> 4, cl = l & 15;
  int rw = tid / 12, jl = tid % 12;

#pragma unroll 7
  for (int p = 0; p < 7; ++p) {
    int e = tid + p * 192;
    int f = e / (KW_ * 48), rem = e % (KW_ * 48), k = rem / 48, c = rem % 48;
    cw[f][k][c] = ldc(conv1_w, (c * F_ + f) * KW_ + k);
  }
#pragma unroll 10
  for (int p = 0; p < 10; ++p) {
    int e = tid + p * 192;
    if (e < 64 * KW_ * 2) {
      int rr = e / (KW_ * 2), rem = e % (KW_ * 2), k = rem / 2, f = rem % 2;
      int n = tile * 64 + rr; if (n > 799) n = 799;
      int tau = t + k;
      float v;
      if (tau < TIN_) v = ldc(x, ((size_t)(b * TIN_ + tau) * N_ + n) * F_ + f);
      else if (tau < TIN_ + TP_) v = (f == 0) ? 0.f : ldc(T, (size_t)(b * TP_ + (tau - TIN_)) * N_ + n);
      else v = ldc(x, ((size_t)(b * TIN_ + 0) * N_ + n) * F_ + f);
      tpw[rr][k][f] = v;
    }
  }
  for (int e = tid; e < 64 * 24; e += 192)
    preS[e / 24][48 + e % 24] = 0;
  __syncthreads();
  {
    int c0 = jl * 4;
    float acc[4][4];
#pragma unroll
    for (int qq = 0; qq < 4; ++qq)
#pragma unroll
      for (int m = 0; m < 4; ++m) acc[qq][m] = ldc(conv1_b, c0 + m);
#pragma unroll
    for (int f = 0; f < 2; ++f)
      for (int k = 0; k < KW_; ++k) {
        const float4 w4 = *(const float4*)&cw[f][k][c0];
        float wvv[4] = {w4.x, w4.y, w4.z, w4.w};
#pragma unroll
        for (int qq = 0; qq < 4; ++qq) {
          float tv = tpw[rw * 4 + qq][k][f];
#pragma unroll
          for (int m = 0; m < 4; ++m) acc[qq][m] += tv * wvv[m];
        }
      }
#pragma unroll
    for (int qq = 0; qq < 4; ++qq)
#pragma unroll
      for (int m = 0; m < 4; ++m)
        preS[rw * 4 + qq][c0 + m] = f2u(acc[qq][m]);
  }
  __syncthreads();
#pragma unroll
  for (int q = 0; q < 3; ++q) {
    int nt = 3 * wv + q;
    int g = nt / 3;
    int jj = (nt - g * 3) * 16 + cl;
    const TI* wl = (g == 0) ? lwz : (g == 1) ? lwr : lwh;
    const TI* bl = (g == 0) ? lbz : (g == 1) ? lbr : lbh;
    s8b Bf0, Bf1;
#pragma unroll
    for (int j = 0; j < 8; ++j) {
      int k0 = cg * 8 + j;
      int k1 = 32 + cg * 8 + j;
      Bf0[j] = (short)f2u(ldc(wl, ((size_t)t * 96 + k0) * 48 + jj));
      Bf1[j] = (k1 < 48) ? (short)f2u(ldc(wl, ((size_t)t * 96 + k1) * 48 + jj)) : (short)0;
    }
#pragma unroll
    for (int mt = 0; mt < 4; ++mt) {
      int nbase = tile * 64 + mt * 16;
      if (nbase >= 800) continue;
      s8b A0 = *(const s8b*)&preS[mt * 16 + cl][cg * 8];
      s8b A1 = *(const s8b*)&preS[mt * 16 + cl][32 + cg * 8];
      f4 acc;
#pragma unroll
      for (int r = 0; r < 4; ++r)
        acc[r] = ldc(bl, ((size_t)t * N_ + (nbase + cg * 4 + r)) * C_ + jj);
      acc = __builtin_amdgcn_mfma_f32_16x16x32_bf16(A0, Bf0, acc, 0, 0, 0);
      acc = __builtin_amdgcn_mfma_f32_16x16x32_bf16(A1, Bf1, acc, 0, 0, 0);
      int grp = b * 50 + tile * 4 + mt;
      size_t idx = ((((size_t)grp * 21 + (11 + t)) * 9 + nt) * 64 + l) * 4;
      ushort4 u;
      u.x = f2u(acc[0]); u.y = f2u(acc[1]); u.z = f2u(acc[2]); u.w = f2u(acc[3]);
      *(ushort4*)((unsigned short*)xfrag + idx) = u;
    }
  }
}

// ---------------- K2: projx (bx<286) + convx (bx>=286), 192 thr ------------
#define PJ_BLKS 286
#define CV_BLKS 260
__global__ __launch_bounds__(192) void k_xc(
    const bf16* att_t, const bf16* att_st,
    const void* Wpt, const void* bpt, const void* Wps, const void* bps,
    const void* xwz, const void* xwr, const void* xwh,
    const void* xbz, const void* xbr, const void* xbh,
    const void* x, const void* T, const void* cw_, const void* cb,
    const void* lwz, const void* lwr, const void* lwh,
    const void* lbz, const void* lbr, const void* lbh, bf16* xfrag) {
  __shared__ __align__(16) char smem[31744];
  int f32 = detect_f32(x);
  int bx = blockIdx.x;
  if (bx < PJ_BLKS) {
    int tile = bx % 13, ty = (bx / 13) % 11, b = bx / 143;
    auto rawT = (unsigned short(*)[72])smem;
    auto rawS = (unsigned short(*)[72])(smem + 9216);
    auto catS = (unsigned short(*)[104])(smem + 18432);
    if (f32)
      projx2_body<float>(rawT, rawS, catS, tile, ty, b, att_t, att_st,
                         (const float*)Wpt, (const float*)bpt, (const float*)Wps,
                         (const float*)bps, (const float*)xwz, (const float*)xwr,
                         (const float*)xwh, (const float*)xbz, (const float*)xbr,
                         (const float*)xbh, xfrag);
    else
      projx2_body<bf16>(rawT, rawS, catS, tile, ty, b, att_t, att_st,
                        (const bf16*)Wpt, (const bf16*)bpt, (const bf16*)Wps,
                        (const bf16*)bps, (const bf16*)xwz, (const bf16*)xwr,
                        (const bf16*)xwh, (const bf16*)xbz, (const bf16*)xbr,
                        (const bf16*)xbh, xfrag);
  } else {
    int cblk = bx - PJ_BLKS;
    int tile = cblk % 13, t = (cblk / 13) % 10, b = cblk / 130;
    auto tpw  = (float(*)[KW_][2])smem;
    auto cw   = (float(*)[KW_][48])(smem + 7168);
    auto preS = (unsigned short(*)[72])(smem + 12544);
    if (f32)
      convx5_body<float>(tpw, cw, preS, tile, t, b,
                         (const float*)x, (const float*)T, (const float*)cw_, (const float*)cb,
                         (const float*)lwz, (const float*)lwr, (const float*)lwh,
                         (const float*)lbz, (const float*)lbr, (const float*)lbh, xfrag);
    else
      convx5_body<bf16>(tpw, cw, preS, tile, t, b,
                        (const bf16*)x, (const bf16*)T, (const bf16*)cw_, (const bf16*)cb,
                        (const bf16*)lwz, (const bf16*)lwr, (const bf16*)lwh,
                        (const bf16*)lbz, (const bf16*)lbr, (const bf16*)lbh, xfrag);
  }
}

// ---------------- K3: MFMA GRU v11 — DMA pipeline, wait-shadowed ----------
template <typename TI, typename TO>
__device__ __forceinline__ void gru11_body(
    unsigned short (*wbuf)[9216], unsigned short (*xbuf)[2560],
    unsigned short* hT, unsigned short* rhT,
    const unsigned short* xfrag, const unsigned short* pwb,
    const TI* Wout, const TI* bout, TO* out) {
  int l = threadIdx.x;          // 64
  int cg = l >> 4, cl = l & 15;
  int blk = blockIdx.x;
  int b = blk / 50;
  int n0 = (blk % 50) * 16;

  for (int e = l; e < 1152; e += 64) { hT[e] = 0; rhT[e] = 0; }
  float bo = ldc(bout, 0);
  s8b WoB0, WoB1;   // Wout B-fragment (col 0 only)
#pragma unroll
  for (int j = 0; j < 8; ++j) {
    int k0 = cg * 8 + j;
    int k1 = 32 + cg * 8 + j;
    WoB0[j] = (cl == 0) ? (short)f2u(ldc(Wout, k0)) : (short)0;
    WoB1[j] = (cl == 0 && k1 < 48) ? (short)f2u(ldc(Wout, k1)) : (short)0;
  }
  float ho[3][4];
#pragma unroll
  for (int nt = 0; nt < 3; ++nt)
#pragma unroll
    for (int r = 0; r < 4; ++r) ho[nt][r] = 0.f;

  const unsigned short* xg = xfrag + (size_t)blk * 48384;
#pragma unroll
  for (int i = 0; i < 18; ++i) gll16(pwb + i * 512 + l * 8, &wbuf[0][i * 512]);
#pragma unroll
  for (int i = 0; i < 5; ++i) gll16(xg + i * 512 + l * 8, &xbuf[0][i * 512]);
  asm volatile("" ::: "memory");

  for (int step = 0; step < 21; ++step) {
    int cur = step & 1;
    s8b hA0 = *(const s8b*)&hT[cl * 72 + cg * 8];
    s8b hA1 = *(const s8b*)&hT[cl * 72 + 32 + cg * 8];
    if (step >= 12) {  // decoder output t = step-12 (shadows DMA wait)
      f4 oacc = {bo, bo, bo, bo};
      oacc = __builtin_amdgcn_mfma_f32_16x16x32_bf16(hA0, WoB0, oacc, 0, 0, 0);
      oacc = __builtin_amdgcn_mfma_f32_16x16x32_bf16(hA1, WoB1, oacc, 0, 0, 0);
      if (cl == 0) {
        int t = step - 12;
#pragma unroll
        for (int r = 0; r < 4; ++r)
          sto(out, ((size_t)b * TP_ + t) * N_ + n0 + cg * 4 + r, oacc[r]);
      }
    }
    asm volatile("s_waitcnt vmcnt(0)" ::: "memory");
    s8b Wz[3][2], Wr[3][2], Wh[3][2];
    const unsigned short* wb = wbuf[cur];
#pragma unroll
    for (int nt = 0; nt < 3; ++nt)
#pragma unroll
      for (int c = 0; c < 2; ++c) {
        Wz[nt][c] = *(const s8b*)&wb[0 * 3072 + nt * 1024 + c * 512 + l * 8];
        Wr[nt][c] = *(const s8b*)&wb[1 * 3072 + nt * 1024 + c * 512 + l * 8];
        Wh[nt][c] = *(const s8b*)&wb[2 * 3072 + nt * 1024 + c * 512 + l * 8];
      }
    ushort4 cx[9];
#pragma unroll
    for (int gn = 0; gn < 9; ++gn)
      cx[gn] = *(const ushort4*)&xbuf[cur][gn * 256 + l * 4];
    if (step < 20) {
      const unsigned short* wsn = pwb + (size_t)(step + 1) * 9216;
#pragma unroll
      for (int i = 0; i < 18; ++i) gll16(wsn + i * 512 + l * 8, &wbuf[cur ^ 1][i * 512]);
      const unsigned short* xsn = xg + (size_t)(step + 1) * 2304;
#pragma unroll
      for (int i = 0; i < 5; ++i) gll16(xsn + i * 512 + l * 8, &xbuf[cur ^ 1][i * 512]);
    }
    f4 az[3], ar[3];
#pragma unroll
    for (int nt = 0; nt < 3; ++nt) {
      f4 cz = {bfu(cx[nt].x), bfu(cx[nt].y), bfu(cx[nt].z), bfu(cx[nt].w)};
      cz = __builtin_amdgcn_mfma_f32_16x16x32_bf16(hA0, Wz[nt][0], cz, 0, 0, 0);
      cz = __builtin_amdgcn_mfma_f32_16x16x32_bf16(hA1, Wz[nt][1], cz, 0, 0, 0);
      az[nt] = cz;
      f4 cr = {bfu(cx[3 + nt].x), bfu(cx[3 + nt].y), bfu(cx[3 + nt].z), bfu(cx[3 + nt].w)};
      cr = __builtin_amdgcn_mfma_f32_16x16x32_bf16(hA0, Wr[nt][0], cr, 0, 0, 0);
      cr = __builtin_amdgcn_mfma_f32_16x16x32_bf16(hA1, Wr[nt][1], cr, 0, 0, 0);
      ar[nt] = cr;
    }
    float z[3][4];
#pragma unroll
    for (int nt = 0; nt < 3; ++nt)
#pragma unroll
      for (int r = 0; r < 4; ++r) {
        z[nt][r] = sigm(az[nt][r]);
        float rv = sigm(ar[nt][r]) * ho[nt][r];
        rhT[(cg * 4 + r) * 72 + nt * 16 + cl] = f2u(rv);
      }
    asm volatile("" ::: "memory");
    s8b rA0 = *(const s8b*)&rhT[cl * 72 + cg * 8];
    s8b rA1 = *(const s8b*)&rhT[cl * 72 + 32 + cg * 8];
    f4 ah[3];
#pragma unroll
    for (int nt = 0; nt < 3; ++nt) {
      f4 ch = {bfu(cx[6 + nt].x), bfu(cx[6 + nt].y), bfu(cx[6 + nt].z), bfu(cx[6 + nt].w)};
      ch = __builtin_amdgcn_mfma_f32_16x16x32_bf16(rA0, Wh[nt][0], ch, 0, 0, 0);
      ch = __builtin_amdgcn_mfma_f32_16x16x32_bf16(rA1, Wh[nt][1], ch, 0, 0, 0);
      ah[nt] = ch;
    }
#pragma unroll
    for (int nt = 0; nt < 3; ++nt)
#pragma unroll
      for (int r = 0; r < 4; ++r) {
        float hn = (1.f - z[nt][r]) * ho[nt][r] + z[nt][r] * tanh_(ah[nt][r]);
        ho[nt][r] = hn;
        hT[(cg * 4 + r) * 72 + nt * 16 + cl] = f2u(hn);
      }
    asm volatile("" ::: "memory");
  }
  // epilogue: output t=9 from final h
  {
    s8b hA0 = *(const s8b*)&hT[cl * 72 + cg * 8];
    s8b hA1 = *(const s8b*)&hT[cl * 72 + 32 + cg * 8];
    f4 oacc = {bo, bo, bo, bo};
    oacc = __builtin_amdgcn_mfma_f32_16x16x32_bf16(hA0, WoB0, oacc, 0, 0, 0);
    oacc = __builtin_amdgcn_mfma_f32_16x16x32_bf16(hA1, WoB1, oacc, 0, 0, 0);
    if (cl == 0) {
#pragma unroll
      for (int r = 0; r < 4; ++r)
        sto(out, ((size_t)b * TP_ + 9) * N_ + n0 + cg * 4 + r, oacc[r]);
    }
  }
}
__global__ __launch_bounds__(64) void k_gru11(
    const void* xin, const bf16* xfrag, const bf16* pwb,
    const void* Wout, const void* bout, void* out) {
  __shared__ alignas(16) unsigned short wbuf[2][9216];
  __shared__ alignas(16) unsigned short xbuf[2][2560];
  __shared__ alignas(16) unsigned short hT[1152];
  __shared__ alignas(16) unsigned short rhT[1152];
  int f32 = detect_f32(xin);
  if (f32)
    gru11_body<float, float>(wbuf, xbuf, hT, rhT,
                             (const unsigned short*)xfrag, (const unsigned short*)pwb,
                             (const float*)Wout, (const float*)bout, (float*)out);
  else
    gru11_body<bf16, bf16>(wbuf, xbuf, hT, rhT,
                           (const unsigned short*)xfrag, (const unsigned short*)pwb,
                           (const bf16*)Wout, (const bf16*)bout, (bf16*)out);
}

// ---------------------------------------------------------------------------
extern "C" void kernel_launch(void* const* d_in, const int* in_sizes, int n_in,
                              void* d_out, int out_size, void* d_ws, size_t ws_size,
                              hipStream_t stream) {
  (void)in_sizes; (void)n_in; (void)out_size; (void)ws_size;
  const void* x       = d_in[0];
  const void* T       = d_in[1];
  const void* Wq_t    = d_in[3];
  const void* Wk_t    = d_in[4];
  const void* Wv_t    = d_in[5];
  const void* Wq_st   = d_in[6];
  const void* Wk_st   = d_in[7];
  const void* Wv_st   = d_in[8];
  const void* bq_t    = d_in[9];
  const void* bk_t    = d_in[10];
  const void* bv_t    = d_in[11];
  const void* bq_st   = d_in[12];
  const void* bk_st   = d_in[13];
  const void* bv_st   = d_in[14];
  const void* conv1_w = d_in[15];
  const void* conv1_b = d_in[16];
  const void* Wproj_t = d_in[17];
  const void* bproj_t = d_in[18];
  const void* Wproj_st= d_in[19];
  const void* bproj_st= d_in[20];
  const void* xhr_wz  = d_in[21];
  const void* xhr_wr  = d_in[22];
  const void* xhr_wh  = d_in[23];
  const void* xhr_bz  = d_in[24];
  const void* xhr_br  = d_in[25];
  const void* xhr_bh  = d_in[26];
  const void* last_wz = d_in[27];
  const void* last_wr = d_in[28];
  const void* last_wh = d_in[29];
  const void* last_bz = d_in[30];
  const void* last_br = d_in[31];
  const void* last_bh = d_in[32];
  const void* Wout    = d_in[33];
  const void* bout    = d_in[34];

  // ws layout (~13.2 MB; proven safe earlier)
  char* wsb = (char*)d_ws;
  bf16* att_t  = (bf16*)(wsb + 256);                     // 2*11*800*48
  bf16* att_st = att_t + (size_t)2 * 11 * 800 * 48;
  bf16* xfrag  = att_st + (size_t)2 * 11 * 800 * 48;     // 100*21*9*64*4 elems
  bf16* pwb    = xfrag + (size_t)100 * 21 * 9 * 64 * 4;  // 21*9216 (compact)

  k_phase1<<<SP_BLKS + TMP_BLKS + PK_BLKS, 832, 0, stream>>>(
      x, Wq_t, Wk_t, Wv_t, bq_t, bk_t, bv_t,
      Wq_st, Wk_st, Wv_st, bq_st, bk_st, bv_st,
      xhr_wz, xhr_wr, xhr_wh, last_wz, last_wr, last_wh,
      att_t, att_st, pwb);
  k_xc<<<PJ_BLKS + CV_BLKS, 192, 0, stream>>>(
      att_t, att_st, Wproj_t, bproj_t, Wproj_st, bproj_st,
      xhr_wz, xhr_wr, xhr_wh, xhr_bz, xhr_br, xhr_bh,
      x, T, conv1_w, conv1_b, last_wz, last_wr, last_wh,
      last_bz, last_br, last_bh, xfrag);
  k_gru11<<<100, 64, 0, stream>>>(
      x, xfrag, pwb, Wout, bout, d_out);
}

// Round 18
// 117.658 us; speedup vs baseline: 1.1083x; 1.0190x over previous
//
#include <hip/hip_runtime.h>
#include <hip/hip_bf16.h>

typedef __hip_bfloat16 bf16;
typedef __attribute__((ext_vector_type(8))) short s8b;   // 8 bf16 (4 VGPR)
typedef __attribute__((ext_vector_type(4))) float f4;    // MFMA C/D

#define B_ 2
#define TIN_ 12
#define N_ 800
#define F_ 2
#define H_ 6
#define D_ 8
#define C_ 48
#define TP_ 10
#define KW_ 14
#define SCALE 0.35355339059327373f  // 1/sqrt(8)
#define LOG2E 1.4426950408889634f

#define PIN(v) asm volatile("" :: "v"(v))

__device__ __forceinline__ float sigm(float x) { return 1.0f / (1.0f + __expf(-x)); }
__device__ __forceinline__ float tanh_(float x) {
  float e = __expf(-2.0f * x);
  return 2.0f / (1.0f + e) - 1.0f;
}
__device__ __forceinline__ float exp2_(float x) { return __builtin_amdgcn_exp2f(x); }
__device__ __forceinline__ float bfu(unsigned short u) {
  return __uint_as_float((unsigned)u << 16);
}
__device__ __forceinline__ unsigned short f2u(float v) {
  return __bfloat16_as_ushort(__float2bfloat16(v));
}
__device__ __forceinline__ float ldc(const float* p, size_t i) { return p[i]; }
__device__ __forceinline__ float ldc(const bf16* p, size_t i) { return __bfloat162float(p[i]); }
__device__ __forceinline__ void sto(float* p, size_t i, float v) { p[i] = v; }
__device__ __forceinline__ void sto(bf16* p, size_t i, float v) { p[i] = __float2bfloat16(v); }
// per-wave dtype detection: f32 data -> low bf16 halves have wild exponents
__device__ __forceinline__ int detect_f32(const void* xv) {
  const unsigned int* xw = (const unsigned int*)xv;
  unsigned int w = xw[threadIdx.x & 63];
  int e = (w >> 7) & 0xFF;
  int bad = ((e >= 1 && e < 96) || (e > 150)) ? 1 : 0;
  unsigned long long m = __ballot(bad);
  return (__popcll(m) >= 16) ? 1 : 0;
}

// ---------------- pack body: compact MFMA B-fragments ----------------------
template <typename TI>
__device__ __forceinline__ void pack_body(
    int gid, const TI* xwz, const TI* xwr, const TI* xwh,
    const TI* lwz, const TI* lwr, const TI* lwh, bf16* pwb) {
  const int total = 21 * 9216;
  if (gid >= total) return;
  int step = gid / 9216, r = gid % 9216;
  int g = r / 3072;  r %= 3072;
  int nt = r / 1024; r %= 1024;
  int c = r / 512;   r %= 512;
  int lane = r / 8, j = r % 8;
  int k = 32 * c + (lane >> 4) * 8 + j;
  int n = nt * 16 + (lane & 15);
  float v = 0.f;
  if (k < 48) {
    if (step < 11) {
      int t = step + 1;
      const TI* w = (g == 0) ? xwz : (g == 1) ? xwr : xwh;
      v = ldc(w, ((size_t)t * 144 + 96 + k) * 48 + n);
    } else {
      int t = step - 11;
      const TI* w = (g == 0) ? lwz : (g == 1) ? lwr : lwh;
      v = ldc(w, ((size_t)t * 96 + 48 + k) * 48 + n);
    }
  }
  pwb[gid] = __float2bfloat16(v);
}

// ---------------- temporal body (per-element gid) --------------------------
template <typename TI>
__device__ __forceinline__ void temporal_body(
    int gid, const TI* x, const TI* Wq, const TI* Wk, const TI* Wv,
    const TI* bq, const TI* bk, const TI* bv, bf16* att_t) {
  const int total = B_ * (TIN_ - 1) * H_ * N_;
  if (gid >= total) return;
  int n = gid % N_;
  int r = gid / N_;
  int h = r % H_;  r /= H_;
  int t = (r % (TIN_ - 1)) + 1;
  int b = r / (TIN_ - 1);

  float wq[F_][D_], wk[F_][D_], wv[F_][D_], bqv[D_], bkv[D_], bvv[D_];
#pragma unroll
  for (int f = 0; f < F_; ++f)
#pragma unroll
    for (int d = 0; d < D_; ++d) {
      wq[f][d] = ldc(Wq, (h * F_ + f) * D_ + d);
      wk[f][d] = ldc(Wk, (h * F_ + f) * D_ + d);
      wv[f][d] = ldc(Wv, (h * F_ + f) * D_ + d);
    }
#pragma unroll
  for (int d = 0; d < D_; ++d) {
    bqv[d] = ldc(bq, h * D_ + d);
    bkv[d] = ldc(bk, h * D_ + d);
    bvv[d] = ldc(bv, h * D_ + d);
  }
  float xt0 = ldc(x, ((b * TIN_ + t) * N_ + n) * F_ + 0);
  float xt1 = ldc(x, ((b * TIN_ + t) * N_ + n) * F_ + 1);
  float q[D_];
#pragma unroll
  for (int d = 0; d < D_; ++d) q[d] = xt0 * wq[0][d] + xt1 * wq[1][d] + bqv[d];

  float sc[TIN_];
  float mx = -1e30f;
#pragma unroll
  for (int s = 0; s < TIN_; ++s) {
    float xs0 = ldc(x, ((b * TIN_ + s) * N_ + n) * F_ + 0);
    float xs1 = ldc(x, ((b * TIN_ + s) * N_ + n) * F_ + 1);
    float dot = 0.f;
#pragma unroll
    for (int d = 0; d < D_; ++d)
      dot += q[d] * (xs0 * wk[0][d] + xs1 * wk[1][d] + bkv[d]);
    dot *= SCALE;
    sc[s] = (s <= t) ? dot : -1e30f;
    mx = fmaxf(mx, sc[s]);
  }
  float sum = 0.f;
#pragma unroll
  for (int s = 0; s < TIN_; ++s) {
    float p = __expf(sc[s] - mx);
    sc[s] = p;
    sum += p;
  }
  float inv = 1.0f / sum;
  float acc[D_];
#pragma unroll
  for (int d = 0; d < D_; ++d) acc[d] = 0.f;
#pragma unroll
  for (int s = 0; s < TIN_; ++s) {
    float xs0 = ldc(x, ((b * TIN_ + s) * N_ + n) * F_ + 0);
    float xs1 = ldc(x, ((b * TIN_ + s) * N_ + n) * F_ + 1);
#pragma unroll
    for (int d = 0; d < D_; ++d)
      acc[d] += sc[s] * (xs0 * wv[0][d] + xs1 * wv[1][d] + bvv[d]);
  }
  bf16* o = att_t + ((size_t)((b * 11 + (t - 1)) * N_ + n)) * C_ + h * D_;
#pragma unroll
  for (int d = 0; d < D_; ++d) o[d] = __float2bfloat16(acc[d] * inv);
}

// ---------------- spatial4: rank-2, head-split, shfl-reduced ---------------
template <typename TI>
__device__ __forceinline__ void spatial4_body(
    float2* xs, float (*M)[9], float (*Vw)[3][D_],
    int tile, int ty, int b, int hg,
    const TI* x, const TI* Wq, const TI* Wk, const TI* Wv,
    const TI* bq, const TI* bk, const TI* bv, bf16* att_st) {
  int t = ty + 1;
  int tid = threadIdx.x;

  for (int m = tid; m < N_; m += 832)
    xs[m] = make_float2(ldc(x, ((b * TIN_ + t) * N_ + m) * F_ + 0),
                        ldc(x, ((b * TIN_ + t) * N_ + m) * F_ + 1));
  if (tid < 18) {
    int lh = tid / 9, e = tid % 9, a = e / 3, bb = e % 3;
    int h = hg * 2 + lh;
    float acc = 0.f;
    for (int d = 0; d < 8; ++d) {
      float qa = (a == 0) ? ldc(Wq, (h * 2 + 0) * 8 + d)
               : (a == 1) ? ldc(Wq, (h * 2 + 1) * 8 + d) : ldc(bq, h * 8 + d);
      float kb = (bb == 0) ? ldc(Wk, (h * 2 + 0) * 8 + d)
               : (bb == 1) ? ldc(Wk, (h * 2 + 1) * 8 + d) : ldc(bk, h * 8 + d);
      acc += qa * kb;
    }
    M[lh][e] = acc * SCALE * LOG2E;
  }
  if (tid >= 64 && tid < 64 + 48) {
    int e = tid - 64;
    int lh = e / 24, a = (e % 24) / 8, d = e % 8;
    int h = hg * 2 + lh;
    Vw[lh][a][d] = (a == 0) ? ldc(Wv, (h * 2 + 0) * 8 + d)
                 : (a == 1) ? ldc(Wv, (h * 2 + 1) * 8 + d) : ldc(bv, h * 8 + d);
  }
  __syncthreads();
  if (tid < 800) {
    int row = tid >> 3, ms = tid & 7;
    int n = tile * 100 + row;
    float x0 = xs[n].x, x1 = xs[n].y;
    float A[2], Bc[2], Cc[2];
#pragma unroll
    for (int lh = 0; lh < 2; ++lh) {
      A[lh]  = M[lh][0] * x0 + M[lh][3] * x1 + M[lh][6];
      Bc[lh] = M[lh][1] * x0 + M[lh][4] * x1 + M[lh][7];
      Cc[lh] = M[lh][2] * x0 + M[lh][5] * x1 + M[lh][8];
    }
    float Sp[2] = {0, 0}, S0[2] = {0, 0}, S1[2] = {0, 0};
    for (int m = ms * 100; m < ms * 100 + 100; ++m) {
      float2 xm = xs[m];
#pragma unroll
      for (int lh = 0; lh < 2; ++lh) {
        float p = exp2_(A[lh] * xm.x + Bc[lh] * xm.y + Cc[lh]);
        Sp[lh] += p;
        S0[lh] += p * xm.x;
        S1[lh] += p * xm.y;
      }
    }
#pragma unroll
    for (int lh = 0; lh < 2; ++lh) {
#pragma unroll
      for (int off = 1; off < 8; off <<= 1) {
        Sp[lh] += __shfl_xor(Sp[lh], off);
        S0[lh] += __shfl_xor(S0[lh], off);
        S1[lh] += __shfl_xor(S1[lh], off);
      }
    }
    if (ms == 0) {
      bf16* o = att_st + ((size_t)((b * 11 + ty) * N_ + n)) * C_;
#pragma unroll
      for (int lh = 0; lh < 2; ++lh) {
        int h = hg * 2 + lh;
        float inv = 1.f / Sp[lh];
#pragma unroll
        for (int d = 0; d < 8; ++d)
          o[h * 8 + d] = __float2bfloat16(
              (S0[lh] * Vw[lh][0][d] + S1[lh] * Vw[lh][1][d] + Sp[lh] * Vw[lh][2][d]) * inv);
      }
    }
  }
}

// ---------------- K1: spatial4 + temporal + pack (LDS = 6.9 KB) ------------
#define SP_BLKS 528
#define TMP_BLKS 127
#define PK_BLKS 233
__global__ __launch_bounds__(832) void k_phase1(
    const void* x,
    const void* Wq_t, const void* Wk_t, const void* Wv_t,
    const void* bq_t, const void* bk_t, const void* bv_t,
    const void* Wq_st, const void* Wk_st, const void* Wv_st,
    const void* bq_st, const void* bk_st, const void* bv_st,
    const void* xwz, const void* xwr, const void* xwh,
    const void* lwz, const void* lwr, const void* lwh,
    bf16* att_t, bf16* att_st, bf16* pwb) {
  __shared__ float2 xs[N_];
  __shared__ float M[2][9];
  __shared__ float Vw[2][3][D_];
  int f32 = detect_f32(x);
  int bx = blockIdx.x;
  if (bx < SP_BLKS) {
    int tile = bx % 8, ty = (bx / 8) % 11, zz = bx / 88;
    int b = zz / 3, hg = zz % 3;
    if (f32)
      spatial4_body<float>(xs, M, Vw, tile, ty, b, hg,
                           (const float*)x, (const float*)Wq_st, (const float*)Wk_st,
                           (const float*)Wv_st, (const float*)bq_st, (const float*)bk_st,
                           (const float*)bv_st, att_st);
    else
      spatial4_body<bf16>(xs, M, Vw, tile, ty, b, hg,
                          (const bf16*)x, (const bf16*)Wq_st, (const bf16*)Wk_st,
                          (const bf16*)Wv_st, (const bf16*)bq_st, (const bf16*)bk_st,
                          (const bf16*)bv_st, att_st);
  } else if (bx < SP_BLKS + TMP_BLKS) {
    int gid = (bx - SP_BLKS) * 832 + threadIdx.x;
    if (f32)
      temporal_body<float>(gid, (const float*)x, (const float*)Wq_t, (const float*)Wk_t,
                           (const float*)Wv_t, (const float*)bq_t, (const float*)bk_t,
                           (const float*)bv_t, att_t);
    else
      temporal_body<bf16>(gid, (const bf16*)x, (const bf16*)Wq_t, (const bf16*)Wk_t,
                          (const bf16*)Wv_t, (const bf16*)bq_t, (const bf16*)bk_t,
                          (const bf16*)bv_t, att_t);
  } else {
    int gid = (bx - SP_BLKS - TMP_BLKS) * 832 + threadIdx.x;
    if (f32)
      pack_body<float>(gid, (const float*)xwz, (const float*)xwr, (const float*)xwh,
                       (const float*)lwz, (const float*)lwr, (const float*)lwh, pwb);
    else
      pack_body<bf16>(gid, (const bf16*)xwz, (const bf16*)xwr, (const bf16*)xwh,
                      (const bf16*)lwz, (const bf16*)lwr, (const bf16*)lwh, pwb);
  }
}

// ---------------- projx body (MFMA, unchanged math) ------------------------
template <typename TI>
__device__ __forceinline__ void projx2_body(
    unsigned short (*rawT)[72], unsigned short (*rawS)[72], unsigned short (*catS)[104],
    int tile, int ty, int b,
    const bf16* att_t, const bf16* att_st,
    const TI* Wpt, const TI* bpt, const TI* Wps, const TI* bps,
    const TI* xwz, const TI* xwr, const TI* xwh,
    const TI* xbz, const TI* xbr, const TI* xbh,
    bf16* xfrag) {
  int t = ty + 1;
  int tid = threadIdx.x;
  int wv = tid >> 6, l = tid & 63;
  int cg = l >> 4, cl = l & 15;

  for (int e = tid; e < 64 * 72; e += 192) {
    int rr = e / 72, c = e % 72;
    int n = tile * 64 + rr; if (n > 799) n = 799;
    size_t base = ((size_t)((b * 11 + ty) * N_ + n)) * C_;
    rawT[rr][c] = (c < 48) ? __bfloat16_as_ushort(att_t[base + c]) : (unsigned short)0;
    rawS[rr][c] = (c < 48) ? __bfloat16_as_ushort(att_st[base + c]) : (unsigned short)0;
  }
  __syncthreads();
#pragma unroll
  for (int q = 0; q < 2; ++q) {
    int nt = 2 * wv + q;
    int half = nt / 3;
    int ncol = (nt - half * 3) * 16 + cl;
    float bias = half ? ldc(bps, ncol) : ldc(bpt, ncol);
    s8b Bf0, Bf1;
#pragma unroll
    for (int j = 0; j < 8; ++j) {
      int k0 = cg * 8 + j;
      int k1 = 32 + cg * 8 + j;
      Bf0[j] = (short)f2u(half ? ldc(Wps, (size_t)k0 * 48 + ncol)
                               : ldc(Wpt, (size_t)k0 * 48 + ncol));
      Bf1[j] = (k1 < 48) ? (short)f2u(half ? ldc(Wps, (size_t)k1 * 48 + ncol)
                                           : ldc(Wpt, (size_t)k1 * 48 + ncol))
                         : (short)0;
    }
    unsigned short (*raw)[72] = half ? rawS : rawT;
#pragma unroll
    for (int mt = 0; mt < 4; ++mt) {
      s8b A0 = *(const s8b*)&raw[mt * 16 + cl][cg * 8];
      s8b A1 = *(const s8b*)&raw[mt * 16 + cl][32 + cg * 8];
      f4 acc = {bias, bias, bias, bias};
      acc = __builtin_amdgcn_mfma_f32_16x16x32_bf16(A0, Bf0, acc, 0, 0, 0);
      acc = __builtin_amdgcn_mfma_f32_16x16x32_bf16(A1, Bf1, acc, 0, 0, 0);
#pragma unroll
      for (int r = 0; r < 4; ++r)
        catS[mt * 16 + cg * 4 + r][nt * 16 + cl] = f2u(acc[r]);
    }
  }
  __syncthreads();
#pragma unroll
  for (int q = 0; q < 3; ++q) {
    int nt = 3 * wv + q;
    int g = nt / 3;
    int jj = (nt - g * 3) * 16 + cl;
    const TI* wx = (g == 0) ? xwz : (g == 1) ? xwr : xwh;
    const TI* bx = (g == 0) ? xbz : (g == 1) ? xbr : xbh;
    s8b Bf[3];
#pragma unroll
    for (int c = 0; c < 3; ++c)
#pragma unroll
      for (int j = 0; j < 8; ++j) {
        int k = c * 32 + cg * 8 + j;
        Bf[c][j] = (short)f2u(ldc(wx, ((size_t)t * 144 + k) * 48 + jj));
      }
#pragma unroll
    for (int mt = 0; mt < 4; ++mt) {
      int nbase = tile * 64 + mt * 16;
      if (nbase >= 800) continue;
      s8b A0 = *(const s8b*)&catS[mt * 16 + cl][cg * 8];
      s8b A1 = *(const s8b*)&catS[mt * 16 + cl][32 + cg * 8];
      s8b A2 = *(const s8b*)&catS[mt * 16 + cl][64 + cg * 8];
      f4 acc;
#pragma unroll
      for (int r = 0; r < 4; ++r)
        acc[r] = ldc(bx, ((size_t)t * N_ + (nbase + cg * 4 + r)) * C_ + jj);
      acc = __builtin_amdgcn_mfma_f32_16x16x32_bf16(A0, Bf[0], acc, 0, 0, 0);
      acc = __builtin_amdgcn_mfma_f32_16x16x32_bf16(A1, Bf[1], acc, 0, 0, 0);
      acc = __builtin_amdgcn_mfma_f32_16x16x32_bf16(A2, Bf[2], acc, 0, 0, 0);
      int grp = b * 50 + tile * 4 + mt;
      size_t idx = ((((size_t)grp * 21 + ty) * 9 + nt) * 64 + l) * 4;
      ushort4 u;
      u.x = f2u(acc[0]); u.y = f2u(acc[1]); u.z = f2u(acc[2]); u.w = f2u(acc[3]);
      *(ushort4*)((unsigned short*)xfrag + idx) = u;
    }
  }
}

// ---------------- convx body (192 threads, all active) ---------------------
template <typename TI>
__device__ __forceinline__ void convx5_body(
    float (*tpw)[KW_][2], float (*cw)[KW_][48], unsigned short (*preS)[72],
    int tile, int t, int b,
    const TI* x, const TI* T,
    const TI* conv1_w, const TI* conv1_b,
    const TI* lwz, const TI* lwr, const TI* lwh,
    const TI* lbz, const TI* lbr, const TI* lbh,
    bf16* xfrag) {
  int tid = threadIdx.x;
  int wv = tid >> 6, l = tid & 63;
  int cg = l >> 4, cl = l & 15;
  int rw = tid / 12, jl = tid % 12;

#pragma unroll 7
  for (int p = 0; p < 7; ++p) {
    int e = tid + p * 192;
    int f = e / (KW_ * 48), rem = e % (KW_ * 48), k = rem / 48, c = rem % 48;
    cw[f][k][c] = ldc(conv1_w, (c * F_ + f) * KW_ + k);
  }
#pragma unroll 10
  for (int p = 0; p < 10; ++p) {
    int e = tid + p * 192;
    if (e < 64 * KW_ * 2) {
      int rr = e / (KW_ * 2), rem = e % (KW_ * 2), k = rem / 2, f = rem % 2;
      int n = tile * 64 + rr; if (n > 799) n = 799;
      int tau = t + k;
      float v;
      if (tau < TIN_) v = ldc(x, ((size_t)(b * TIN_ + tau) * N_ + n) * F_ + f);
      else if (tau < TIN_ + TP_) v = (f == 0) ? 0.f : ldc(T, (size_t)(b * TP_ + (tau - TIN_)) * N_ + n);
      else v = ldc(x, ((size_t)(b * TIN_ + 0) * N_ + n) * F_ + f);
      tpw[rr][k][f] = v;
    }
  }
  for (int e = tid; e < 64 * 24; e += 192)
    preS[e / 24][48 + e % 24] = 0;
  __syncthreads();
  {
    int c0 = jl * 4;
    float acc[4][4];
#pragma unroll
    for (int qq = 0; qq < 4; ++qq)
#pragma unroll
      for (int m = 0; m < 4; ++m) acc[qq][m] = ldc(conv1_b, c0 + m);
#pragma unroll
    for (int f = 0; f < 2; ++f)
      for (int k = 0; k < KW_; ++k) {
        const float4 w4 = *(const float4*)&cw[f][k][c0];
        float wvv[4] = {w4.x, w4.y, w4.z, w4.w};
#pragma unroll
        for (int qq = 0; qq < 4; ++qq) {
          float tv = tpw[rw * 4 + qq][k][f];
#pragma unroll
          for (int m = 0; m < 4; ++m) acc[qq][m] += tv * wvv[m];
        }
      }
#pragma unroll
    for (int qq = 0; qq < 4; ++qq)
#pragma unroll
      for (int m = 0; m < 4; ++m)
        preS[rw * 4 + qq][c0 + m] = f2u(acc[qq][m]);
  }
  __syncthreads();
#pragma unroll
  for (int q = 0; q < 3; ++q) {
    int nt = 3 * wv + q;
    int g = nt / 3;
    int jj = (nt - g * 3) * 16 + cl;
    const TI* wl = (g == 0) ? lwz : (g == 1) ? lwr : lwh;
    const TI* bl = (g == 0) ? lbz : (g == 1) ? lbr : lbh;
    s8b Bf0, Bf1;
#pragma unroll
    for (int j = 0; j < 8; ++j) {
      int k0 = cg * 8 + j;
      int k1 = 32 + cg * 8 + j;
      Bf0[j] = (short)f2u(ldc(wl, ((size_t)t * 96 + k0) * 48 + jj));
      Bf1[j] = (k1 < 48) ? (short)f2u(ldc(wl, ((size_t)t * 96 + k1) * 48 + jj)) : (short)0;
    }
#pragma unroll
    for (int mt = 0; mt < 4; ++mt) {
      int nbase = tile * 64 + mt * 16;
      if (nbase >= 800) continue;
      s8b A0 = *(const s8b*)&preS[mt * 16 + cl][cg * 8];
      s8b A1 = *(const s8b*)&preS[mt * 16 + cl][32 + cg * 8];
      f4 acc;
#pragma unroll
      for (int r = 0; r < 4; ++r)
        acc[r] = ldc(bl, ((size_t)t * N_ + (nbase + cg * 4 + r)) * C_ + jj);
      acc = __builtin_amdgcn_mfma_f32_16x16x32_bf16(A0, Bf0, acc, 0, 0, 0);
      acc = __builtin_amdgcn_mfma_f32_16x16x32_bf16(A1, Bf1, acc, 0, 0, 0);
      int grp = b * 50 + tile * 4 + mt;
      size_t idx = ((((size_t)grp * 21 + (11 + t)) * 9 + nt) * 64 + l) * 4;
      ushort4 u;
      u.x = f2u(acc[0]); u.y = f2u(acc[1]); u.z = f2u(acc[2]); u.w = f2u(acc[3]);
      *(ushort4*)((unsigned short*)xfrag + idx) = u;
    }
  }
}

// ---------------- K2: projx (bx<286) + convx (bx>=286), 192 thr ------------
#define PJ_BLKS 286
#define CV_BLKS 260
__global__ __launch_bounds__(192) void k_xc(
    const bf16* att_t, const bf16* att_st,
    const void* Wpt, const void* bpt, const void* Wps, const void* bps,
    const void* xwz, const void* xwr, const void* xwh,
    const void* xbz, const void* xbr, const void* xbh,
    const void* x, const void* T, const void* cw_, const void* cb,
    const void* lwz, const void* lwr, const void* lwh,
    const void* lbz, const void* lbr, const void* lbh, bf16* xfrag) {
  __shared__ __align__(16) char smem[31744];
  int f32 = detect_f32(x);
  int bx = blockIdx.x;
  if (bx < PJ_BLKS) {
    int tile = bx % 13, ty = (bx / 13) % 11, b = bx / 143;
    auto rawT = (unsigned short(*)[72])smem;
    auto rawS = (unsigned short(*)[72])(smem + 9216);
    auto catS = (unsigned short(*)[104])(smem + 18432);
    if (f32)
      projx2_body<float>(rawT, rawS, catS, tile, ty, b, att_t, att_st,
                         (const float*)Wpt, (const float*)bpt, (const float*)Wps,
                         (const float*)bps, (const float*)xwz, (const float*)xwr,
                         (const float*)xwh, (const float*)xbz, (const float*)xbr,
                         (const float*)xbh, xfrag);
    else
      projx2_body<bf16>(rawT, rawS, catS, tile, ty, b, att_t, att_st,
                        (const bf16*)Wpt, (const bf16*)bpt, (const bf16*)Wps,
                        (const bf16*)bps, (const bf16*)xwz, (const bf16*)xwr,
                        (const bf16*)xwh, (const bf16*)xbz, (const bf16*)xbr,
                        (const bf16*)xbh, xfrag);
  } else {
    int cblk = bx - PJ_BLKS;
    int tile = cblk % 13, t = (cblk / 13) % 10, b = cblk / 130;
    auto tpw  = (float(*)[KW_][2])smem;
    auto cw   = (float(*)[KW_][48])(smem + 7168);
    auto preS = (unsigned short(*)[72])(smem + 12544);
    if (f32)
      convx5_body<float>(tpw, cw, preS, tile, t, b,
                         (const float*)x, (const float*)T, (const float*)cw_, (const float*)cb,
                         (const float*)lwz, (const float*)lwr, (const float*)lwh,
                         (const float*)lbz, (const float*)lbr, (const float*)lbh, xfrag);
    else
      convx5_body<bf16>(tpw, cw, preS, tile, t, b,
                        (const bf16*)x, (const bf16*)T, (const bf16*)cw_, (const bf16*)cb,
                        (const bf16*)lwz, (const bf16*)lwr, (const bf16*)lwh,
                        (const bf16*)lbz, (const bf16*)lbr, (const bf16*)lbh, xfrag);
  }
}

// ---------------- K3: MFMA GRU v12 — register dbuf + asm-pinned prefetch ---
// 100 blocks x 64 thr. NO global_load_lds (compiler alias-conservatism drains
// vmcnt at first LDS op after issue). Plain loads into named register sets;
// asm pins at END of step force early issue + single end-of-step vmcnt wait.
template <bool PF, typename TO>
__device__ __forceinline__ void gru_step12(
    int step, int l, int cg, int cl, int b, int n0,
    s8b (&Wzc)[3][2], s8b (&Wrc)[3][2], s8b (&Whc)[3][2], ushort4 (&cxc)[9],
    s8b (&Wzn)[3][2], s8b (&Wrn)[3][2], s8b (&Whn)[3][2], ushort4 (&cxn)[9],
    const unsigned short* pwb, const unsigned short* xg,
    unsigned short* hT, unsigned short* rhT,
    float (&ho)[3][4], const s8b& WoB0, const s8b& WoB1, float bo, TO* out) {
  s8b hA0 = *(const s8b*)&hT[cl * 72 + cg * 8];
  s8b hA1 = *(const s8b*)&hT[cl * 72 + 32 + cg * 8];
  if (step >= 12) {  // decoder output t = step-12 (h after step-1)
    f4 oacc = {bo, bo, bo, bo};
    oacc = __builtin_amdgcn_mfma_f32_16x16x32_bf16(hA0, WoB0, oacc, 0, 0, 0);
    oacc = __builtin_amdgcn_mfma_f32_16x16x32_bf16(hA1, WoB1, oacc, 0, 0, 0);
    if (cl == 0) {
      int t = step - 12;
#pragma unroll
      for (int r = 0; r < 4; ++r)
        sto(out, ((size_t)b * TP_ + t) * N_ + n0 + cg * 4 + r, oacc[r]);
    }
  }
  if (PF) {  // issue next-step loads into the OTHER named set (plain loads)
    const unsigned short* pb = pwb + (size_t)(step + 1) * 9216 + (size_t)l * 8;
#pragma unroll
    for (int nt = 0; nt < 3; ++nt)
#pragma unroll
      for (int c = 0; c < 2; ++c) {
        Wzn[nt][c] = *(const s8b*)(pb + 0 * 3072 + nt * 1024 + c * 512);
        Wrn[nt][c] = *(const s8b*)(pb + 1 * 3072 + nt * 1024 + c * 512);
        Whn[nt][c] = *(const s8b*)(pb + 2 * 3072 + nt * 1024 + c * 512);
      }
    const unsigned short* xsrc = xg + (size_t)(step + 1) * 2304 + (size_t)l * 4;
#pragma unroll
    for (int gn = 0; gn < 9; ++gn)
      cxn[gn] = *(const ushort4*)(xsrc + gn * 256);
  }
  f4 az[3], ar[3];
#pragma unroll
  for (int nt = 0; nt < 3; ++nt) {
    f4 cz = {bfu(cxc[nt].x), bfu(cxc[nt].y), bfu(cxc[nt].z), bfu(cxc[nt].w)};
    cz = __builtin_amdgcn_mfma_f32_16x16x32_bf16(hA0, Wzc[nt][0], cz, 0, 0, 0);
    cz = __builtin_amdgcn_mfma_f32_16x16x32_bf16(hA1, Wzc[nt][1], cz, 0, 0, 0);
    az[nt] = cz;
    f4 cr = {bfu(cxc[3 + nt].x), bfu(cxc[3 + nt].y), bfu(cxc[3 + nt].z), bfu(cxc[3 + nt].w)};
    cr = __builtin_amdgcn_mfma_f32_16x16x32_bf16(hA0, Wrc[nt][0], cr, 0, 0, 0);
    cr = __builtin_amdgcn_mfma_f32_16x16x32_bf16(hA1, Wrc[nt][1], cr, 0, 0, 0);
    ar[nt] = cr;
  }
  float z[3][4];
#pragma unroll
  for (int nt = 0; nt < 3; ++nt)
#pragma unroll
    for (int r = 0; r < 4; ++r) {
      z[nt][r] = sigm(az[nt][r]);
      float rv = sigm(ar[nt][r]) * ho[nt][r];
      rhT[(cg * 4 + r) * 72 + nt * 16 + cl] = f2u(rv);
    }
  asm volatile("" ::: "memory");  // rh writes before rh A-frag reads (wave DS in-order)
  s8b rA0 = *(const s8b*)&rhT[cl * 72 + cg * 8];
  s8b rA1 = *(const s8b*)&rhT[cl * 72 + 32 + cg * 8];
  f4 ah[3];
#pragma unroll
  for (int nt = 0; nt < 3; ++nt) {
    f4 ch = {bfu(cxc[6 + nt].x), bfu(cxc[6 + nt].y), bfu(cxc[6 + nt].z), bfu(cxc[6 + nt].w)};
    ch = __builtin_amdgcn_mfma_f32_16x16x32_bf16(rA0, Whc[nt][0], ch, 0, 0, 0);
    ch = __builtin_amdgcn_mfma_f32_16x16x32_bf16(rA1, Whc[nt][1], ch, 0, 0, 0);
    ah[nt] = ch;
  }
#pragma unroll
  for (int nt = 0; nt < 3; ++nt)
#pragma unroll
    for (int r = 0; r < 4; ++r) {
      float hn = (1.f - z[nt][r]) * ho[nt][r] + z[nt][r] * tanh_(ah[nt][r]);
      ho[nt][r] = hn;
      hT[(cg * 4 + r) * 72 + nt * 16 + cl] = f2u(hn);
    }
  asm volatile("" ::: "memory");  // h writes before next-step reads
  if (PF) {  // END-OF-STEP PINS: loads must be complete HERE (not at use)
#pragma unroll
    for (int nt = 0; nt < 3; ++nt)
#pragma unroll
      for (int c = 0; c < 2; ++c) {
        PIN(Wzn[nt][c]); PIN(Wrn[nt][c]); PIN(Whn[nt][c]);
      }
#pragma unroll
    for (int gn = 0; gn < 9; ++gn) PIN(cxn[gn]);
  }
}

template <typename TI, typename TO>
__device__ __forceinline__ void gru12_body(
    unsigned short* hT, unsigned short* rhT,
    const unsigned short* xfrag, const unsigned short* pwb,
    const TI* Wout, const TI* bout, TO* out) {
  int l = threadIdx.x;          // 64
  int cg = l >> 4, cl = l & 15;
  int blk = blockIdx.x;
  int b = blk / 50;
  int n0 = (blk % 50) * 16;

  for (int e = l; e < 1152; e += 64) { hT[e] = 0; rhT[e] = 0; }
  float bo = ldc(bout, 0);
  s8b WoB0, WoB1;   // Wout B-fragment (col 0 only)
#pragma unroll
  for (int j = 0; j < 8; ++j) {
    int k0 = cg * 8 + j;
    int k1 = 32 + cg * 8 + j;
    WoB0[j] = (cl == 0) ? (short)f2u(ldc(Wout, k0)) : (short)0;
    WoB1[j] = (cl == 0 && k1 < 48) ? (short)f2u(ldc(Wout, k1)) : (short)0;
  }
  float ho[3][4];
#pragma unroll
  for (int nt = 0; nt < 3; ++nt)
#pragma unroll
    for (int r = 0; r < 4; ++r) ho[nt][r] = 0.f;

  const unsigned short* xg = xfrag + (size_t)blk * 48384;
  s8b WzA[3][2], WrA[3][2], WhA[3][2];
  s8b WzB[3][2], WrB[3][2], WhB[3][2];
  ushort4 cxA[9], cxB[9];
  {  // prologue: set A = step 0
    const unsigned short* pb = pwb + (size_t)l * 8;
#pragma unroll
    for (int nt = 0; nt < 3; ++nt)
#pragma unroll
      for (int c = 0; c < 2; ++c) {
        WzA[nt][c] = *(const s8b*)(pb + 0 * 3072 + nt * 1024 + c * 512);
        WrA[nt][c] = *(const s8b*)(pb + 1 * 3072 + nt * 1024 + c * 512);
        WhA[nt][c] = *(const s8b*)(pb + 2 * 3072 + nt * 1024 + c * 512);
      }
#pragma unroll
    for (int gn = 0; gn < 9; ++gn)
      cxA[gn] = *(const ushort4*)(xg + gn * 256 + l * 4);
  }
  asm volatile("" ::: "memory");  // hT zero-fill ordered before A-frag reads

#pragma unroll 1
  for (int s2 = 0; s2 < 10; ++s2) {
    gru_step12<true>(2 * s2, l, cg, cl, b, n0,
                     WzA, WrA, WhA, cxA, WzB, WrB, WhB, cxB,
                     pwb, xg, hT, rhT, ho, WoB0, WoB1, bo, out);
    gru_step12<true>(2 * s2 + 1, l, cg, cl, b, n0,
                     WzB, WrB, WhB, cxB, WzA, WrA, WhA, cxA,
                     pwb, xg, hT, rhT, ho, WoB0, WoB1, bo, out);
  }
  gru_step12<false>(20, l, cg, cl, b, n0,
                    WzA, WrA, WhA, cxA, WzB, WrB, WhB, cxB,
                    pwb, xg, hT, rhT, ho, WoB0, WoB1, bo, out);
  {  // epilogue: output t=9 from final h
    s8b hA0 = *(const s8b*)&hT[cl * 72 + cg * 8];
    s8b hA1 = *(const s8b*)&hT[cl * 72 + 32 + cg * 8];
    f4 oacc = {bo, bo, bo, bo};
    oacc = __builtin_amdgcn_mfma_f32_16x16x32_bf16(hA0, WoB0, oacc, 0, 0, 0);
    oacc = __builtin_amdgcn_mfma_f32_16x16x32_bf16(hA1, WoB1, oacc, 0, 0, 0);
    if (cl == 0) {
#pragma unroll
      for (int r = 0; r < 4; ++r)
        sto(out, ((size_t)b * TP_ + 9) * N_ + n0 + cg * 4 + r, oacc[r]);
    }
  }
}
__global__ __launch_bounds__(64, 1) void k_gru12(
    const void* xin, const bf16* xfrag, const bf16* pwb,
    const void* Wout, const void* bout, void* out) {
  __shared__ alignas(16) unsigned short hT[1152];
  __shared__ alignas(16) unsigned short rhT[1152];
  int f32 = detect_f32(xin);
  if (f32)
    gru12_body<float, float>(hT, rhT,
                             (const unsigned short*)xfrag, (const unsigned short*)pwb,
                             (const float*)Wout, (const float*)bout, (float*)out);
  else
    gru12_body<bf16, bf16>(hT, rhT,
                           (const unsigned short*)xfrag, (const unsigned short*)pwb,
                           (const bf16*)Wout, (const bf16*)bout, (bf16*)out);
}

// ---------------------------------------------------------------------------
extern "C" void kernel_launch(void* const* d_in, const int* in_sizes, int n_in,
                              void* d_out, int out_size, void* d_ws, size_t ws_size,
                              hipStream_t stream) {
  (void)in_sizes; (void)n_in; (void)out_size; (void)ws_size;
  const void* x       = d_in[0];
  const void* T       = d_in[1];
  const void* Wq_t    = d_in[3];
  const void* Wk_t    = d_in[4];
  const void* Wv_t    = d_in[5];
  const void* Wq_st   = d_in[6];
  const void* Wk_st   = d_in[7];
  const void* Wv_st   = d_in[8];
  const void* bq_t    = d_in[9];
  const void* bk_t    = d_in[10];
  const void* bv_t    = d_in[11];
  const void* bq_st   = d_in[12];
  const void* bk_st   = d_in[13];
  const void* bv_st   = d_in[14];
  const void* conv1_w = d_in[15];
  const void* conv1_b = d_in[16];
  const void* Wproj_t = d_in[17];
  const void* bproj_t = d_in[18];
  const void* Wproj_st= d_in[19];
  const void* bproj_st= d_in[20];
  const void* xhr_wz  = d_in[21];
  const void* xhr_wr  = d_in[22];
  const void* xhr_wh  = d_in[23];
  const void* xhr_bz  = d_in[24];
  const void* xhr_br  = d_in[25];
  const void* xhr_bh  = d_in[26];
  const void* last_wz = d_in[27];
  const void* last_wr = d_in[28];
  const void* last_wh = d_in[29];
  const void* last_bz = d_in[30];
  const void* last_br = d_in[31];
  const void* last_bh = d_in[32];
  const void* Wout    = d_in[33];
  const void* bout    = d_in[34];

  // ws layout (~13.2 MB; proven safe earlier)
  char* wsb = (char*)d_ws;
  bf16* att_t  = (bf16*)(wsb + 256);                     // 2*11*800*48
  bf16* att_st = att_t + (size_t)2 * 11 * 800 * 48;
  bf16* xfrag  = att_st + (size_t)2 * 11 * 800 * 48;     // 100*21*9*64*4 elems
  bf16* pwb    = xfrag + (size_t)100 * 21 * 9 * 64 * 4;  // 21*9216 (compact)

  k_phase1<<<SP_BLKS + TMP_BLKS + PK_BLKS, 832, 0, stream>>>(
      x, Wq_t, Wk_t, Wv_t, bq_t, bk_t, bv_t,
      Wq_st, Wk_st, Wv_st, bq_st, bk_st, bv_st,
      xhr_wz, xhr_wr, xhr_wh, last_wz, last_wr, last_wh,
      att_t, att_st, pwb);
  k_xc<<<PJ_BLKS + CV_BLKS, 192, 0, stream>>>(
      att_t, att_st, Wproj_t, bproj_t, Wproj_st, bproj_st,
      xhr_wz, xhr_wr, xhr_wh, xhr_bz, xhr_br, xhr_bh,
      x, T, conv1_w, conv1_b, last_wz, last_wr, last_wh,
      last_bz, last_br, last_bh, xfrag);
  k_gru12<<<100, 64, 0, stream>>>(
      x, xfrag, pwb, Wout, bout, d_out);
}

// Round 19
// 97.733 us; speedup vs baseline: 1.3342x; 1.2039x over previous
//
#include <hip/hip_runtime.h>
#include <hip/hip_bf16.h>

typedef __hip_bfloat16 bf16;
typedef __attribute__((ext_vector_type(8))) short s8b;   // 8 bf16 (4 VGPR)
typedef __attribute__((ext_vector_type(4))) float f4;    // MFMA C/D

#define B_ 2
#define TIN_ 12
#define N_ 800
#define F_ 2
#define H_ 6
#define D_ 8
#define C_ 48
#define TP_ 10
#define KW_ 14
#define SCALE 0.35355339059327373f  // 1/sqrt(8)
#define LOG2E 1.4426950408889634f

#define PIN(v) asm volatile("" :: "v"(v))

// packed-weight region sizes (elements)
#define PACK_GRU_TOT (21 * 9216)        // 193536: GRU recurrent frags
#define PACK_PWX_TOT (11 * 9 * 3 * 512) // 152064: xhr x-part frags
#define PACK_PWP_TOT (6 * 2 * 512)      //   6144: proj Wp frags
#define PACK_PWL_TOT (10 * 9 * 2 * 512) //  92160: last x-part frags
#define PACK_TOT (PACK_GRU_TOT + PACK_PWX_TOT + PACK_PWP_TOT + PACK_PWL_TOT)

__device__ __forceinline__ float sigm(float x) { return 1.0f / (1.0f + __expf(-x)); }
__device__ __forceinline__ float tanh_(float x) {
  float e = __expf(-2.0f * x);
  return 2.0f / (1.0f + e) - 1.0f;
}
__device__ __forceinline__ float exp2_(float x) { return __builtin_amdgcn_exp2f(x); }
__device__ __forceinline__ float bfu(unsigned short u) {
  return __uint_as_float((unsigned)u << 16);
}
__device__ __forceinline__ unsigned short f2u(float v) {
  return __bfloat16_as_ushort(__float2bfloat16(v));
}
__device__ __forceinline__ float ldc(const float* p, size_t i) { return p[i]; }
__device__ __forceinline__ float ldc(const bf16* p, size_t i) { return __bfloat162float(p[i]); }
__device__ __forceinline__ void sto(float* p, size_t i, float v) { p[i] = v; }
__device__ __forceinline__ void sto(bf16* p, size_t i, float v) { p[i] = __float2bfloat16(v); }
// per-wave dtype detection: f32 data -> low bf16 halves have wild exponents
__device__ __forceinline__ int detect_f32(const void* xv) {
  const unsigned int* xw = (const unsigned int*)xv;
  unsigned int w = xw[threadIdx.x & 63];
  int e = (w >> 7) & 0xFF;
  int bad = ((e >= 1 && e < 96) || (e > 150)) ? 1 : 0;
  unsigned long long m = __ballot(bad);
  return (__popcll(m) >= 16) ? 1 : 0;
}

// ---------------- pack body: ALL MFMA B-fragments --------------------------
template <typename TI>
__device__ __forceinline__ void pack_body(
    int gid, const TI* xwz, const TI* xwr, const TI* xwh,
    const TI* lwz, const TI* lwr, const TI* lwh,
    const TI* Wpt, const TI* Wps, bf16* pwb) {
  if (gid >= PACK_TOT) return;
  float v = 0.f;
  if (gid < PACK_GRU_TOT) {
    int step = gid / 9216, r = gid % 9216;
    int g = r / 3072;  r %= 3072;
    int nt = r / 1024; r %= 1024;
    int c = r / 512;   r %= 512;
    int lane = r / 8, j = r % 8;
    int k = 32 * c + (lane >> 4) * 8 + j;
    int n = nt * 16 + (lane & 15);
    if (k < 48) {
      if (step < 11) {
        int t = step + 1;
        const TI* w = (g == 0) ? xwz : (g == 1) ? xwr : xwh;
        v = ldc(w, ((size_t)t * 144 + 96 + k) * 48 + n);
      } else {
        int t = step - 11;
        const TI* w = (g == 0) ? lwz : (g == 1) ? lwr : lwh;
        v = ldc(w, ((size_t)t * 96 + 48 + k) * 48 + n);
      }
    }
  } else {
    int e2 = gid - PACK_GRU_TOT;
    if (e2 < PACK_PWX_TOT) {       // xhr x-part rows 0:96, t=1..11
      int j = e2 & 7, lane = (e2 >> 3) & 63;
      int c = (e2 >> 9) % 3, nt = (e2 / 1536) % 9, tt = e2 / 13824;
      int t = tt + 1;
      int k = c * 32 + (lane >> 4) * 8 + j;                 // 0..95
      int g = nt / 3, jj = (nt - g * 3) * 16 + (lane & 15); // 0..47
      const TI* w = (g == 0) ? xwz : (g == 1) ? xwr : xwh;
      v = ldc(w, ((size_t)t * 144 + k) * 48 + jj);
    } else {
      int e3 = e2 - PACK_PWX_TOT;
      if (e3 < PACK_PWP_TOT) {     // proj Wp (k 0..47, chunk1 padded)
        int j = e3 & 7, lane = (e3 >> 3) & 63;
        int c = (e3 >> 9) & 1, nt = e3 / 1024;              // nt 0..5
        int k = c * 32 + (lane >> 4) * 8 + j;
        int half = nt / 3, ncol = (nt - half * 3) * 16 + (lane & 15);
        if (k < 48)
          v = half ? ldc(Wps, (size_t)k * 48 + ncol) : ldc(Wpt, (size_t)k * 48 + ncol);
      } else {                     // last x-part rows 0:48, t=0..9
        int e4 = e3 - PACK_PWP_TOT;
        int j = e4 & 7, lane = (e4 >> 3) & 63;
        int c = (e4 >> 9) & 1, nt = (e4 / 1024) % 9, t = e4 / 9216;
        int k = c * 32 + (lane >> 4) * 8 + j;
        int g = nt / 3, jj = (nt - g * 3) * 16 + (lane & 15);
        const TI* w = (g == 0) ? lwz : (g == 1) ? lwr : lwh;
        if (k < 48) v = ldc(w, ((size_t)t * 96 + k) * 48 + jj);
      }
    }
  }
  pwb[gid] = __float2bfloat16(v);
}

// ---------------- temporal body (per-element gid) --------------------------
template <typename TI>
__device__ __forceinline__ void temporal_body(
    int gid, const TI* x, const TI* Wq, const TI* Wk, const TI* Wv,
    const TI* bq, const TI* bk, const TI* bv, bf16* att_t) {
  const int total = B_ * (TIN_ - 1) * H_ * N_;
  if (gid >= total) return;
  int n = gid % N_;
  int r = gid / N_;
  int h = r % H_;  r /= H_;
  int t = (r % (TIN_ - 1)) + 1;
  int b = r / (TIN_ - 1);

  float wq[F_][D_], wk[F_][D_], wv[F_][D_], bqv[D_], bkv[D_], bvv[D_];
#pragma unroll
  for (int f = 0; f < F_; ++f)
#pragma unroll
    for (int d = 0; d < D_; ++d) {
      wq[f][d] = ldc(Wq, (h * F_ + f) * D_ + d);
      wk[f][d] = ldc(Wk, (h * F_ + f) * D_ + d);
      wv[f][d] = ldc(Wv, (h * F_ + f) * D_ + d);
    }
#pragma unroll
  for (int d = 0; d < D_; ++d) {
    bqv[d] = ldc(bq, h * D_ + d);
    bkv[d] = ldc(bk, h * D_ + d);
    bvv[d] = ldc(bv, h * D_ + d);
  }
  float xt0 = ldc(x, ((b * TIN_ + t) * N_ + n) * F_ + 0);
  float xt1 = ldc(x, ((b * TIN_ + t) * N_ + n) * F_ + 1);
  float q[D_];
#pragma unroll
  for (int d = 0; d < D_; ++d) q[d] = xt0 * wq[0][d] + xt1 * wq[1][d] + bqv[d];

  float sc[TIN_];
  float mx = -1e30f;
#pragma unroll
  for (int s = 0; s < TIN_; ++s) {
    float xs0 = ldc(x, ((b * TIN_ + s) * N_ + n) * F_ + 0);
    float xs1 = ldc(x, ((b * TIN_ + s) * N_ + n) * F_ + 1);
    float dot = 0.f;
#pragma unroll
    for (int d = 0; d < D_; ++d)
      dot += q[d] * (xs0 * wk[0][d] + xs1 * wk[1][d] + bkv[d]);
    dot *= SCALE;
    sc[s] = (s <= t) ? dot : -1e30f;
    mx = fmaxf(mx, sc[s]);
  }
  float sum = 0.f;
#pragma unroll
  for (int s = 0; s < TIN_; ++s) {
    float p = __expf(sc[s] - mx);
    sc[s] = p;
    sum += p;
  }
  float inv = 1.0f / sum;
  float acc[D_];
#pragma unroll
  for (int d = 0; d < D_; ++d) acc[d] = 0.f;
#pragma unroll
  for (int s = 0; s < TIN_; ++s) {
    float xs0 = ldc(x, ((b * TIN_ + s) * N_ + n) * F_ + 0);
    float xs1 = ldc(x, ((b * TIN_ + s) * N_ + n) * F_ + 1);
#pragma unroll
    for (int d = 0; d < D_; ++d)
      acc[d] += sc[s] * (xs0 * wv[0][d] + xs1 * wv[1][d] + bvv[d]);
  }
  bf16* o = att_t + ((size_t)((b * 11 + (t - 1)) * N_ + n)) * C_ + h * D_;
#pragma unroll
  for (int d = 0; d < D_; ++d) o[d] = __float2bfloat16(acc[d] * inv);
}

// ---------------- spatial4: rank-2, head-split, shfl-reduced ---------------
// Cc (q-side constant coeff of k-bias) cancels in softmax -> dropped.
template <typename TI>
__device__ __forceinline__ void spatial4_body(
    float2* xs, float (*M)[9], float (*Vw)[3][D_],
    int tile, int ty, int b, int hg,
    const TI* x, const TI* Wq, const TI* Wk, const TI* Wv,
    const TI* bq, const TI* bk, const TI* bv, bf16* att_st) {
  int t = ty + 1;
  int tid = threadIdx.x;

  for (int m = tid; m < N_; m += 832)
    xs[m] = make_float2(ldc(x, ((b * TIN_ + t) * N_ + m) * F_ + 0),
                        ldc(x, ((b * TIN_ + t) * N_ + m) * F_ + 1));
  if (tid < 18) {
    int lh = tid / 9, e = tid % 9, a = e / 3, bb = e % 3;
    int h = hg * 2 + lh;
    float acc = 0.f;
    for (int d = 0; d < 8; ++d) {
      float qa = (a == 0) ? ldc(Wq, (h * 2 + 0) * 8 + d)
               : (a == 1) ? ldc(Wq, (h * 2 + 1) * 8 + d) : ldc(bq, h * 8 + d);
      float kb = (bb == 0) ? ldc(Wk, (h * 2 + 0) * 8 + d)
               : (bb == 1) ? ldc(Wk, (h * 2 + 1) * 8 + d) : ldc(bk, h * 8 + d);
      acc += qa * kb;
    }
    M[lh][e] = acc * SCALE * LOG2E;
  }
  if (tid >= 64 && tid < 64 + 48) {
    int e = tid - 64;
    int lh = e / 24, a = (e % 24) / 8, d = e % 8;
    int h = hg * 2 + lh;
    Vw[lh][a][d] = (a == 0) ? ldc(Wv, (h * 2 + 0) * 8 + d)
                 : (a == 1) ? ldc(Wv, (h * 2 + 1) * 8 + d) : ldc(bv, h * 8 + d);
  }
  __syncthreads();
  if (tid < 800) {
    int row = tid >> 3, ms = tid & 7;
    int n = tile * 100 + row;
    float x0 = xs[n].x, x1 = xs[n].y;
    float A[2], Bc[2];
#pragma unroll
    for (int lh = 0; lh < 2; ++lh) {
      A[lh]  = M[lh][0] * x0 + M[lh][3] * x1 + M[lh][6];
      Bc[lh] = M[lh][1] * x0 + M[lh][4] * x1 + M[lh][7];
    }
    float Sp[2] = {0, 0}, S0[2] = {0, 0}, S1[2] = {0, 0};
    for (int m = ms * 100; m < ms * 100 + 100; ++m) {
      float2 xm = xs[m];
#pragma unroll
      for (int lh = 0; lh < 2; ++lh) {
        float p = exp2_(A[lh] * xm.x + Bc[lh] * xm.y);
        Sp[lh] += p;
        S0[lh] += p * xm.x;
        S1[lh] += p * xm.y;
      }
    }
#pragma unroll
    for (int lh = 0; lh < 2; ++lh) {
#pragma unroll
      for (int off = 1; off < 8; off <<= 1) {
        Sp[lh] += __shfl_xor(Sp[lh], off);
        S0[lh] += __shfl_xor(S0[lh], off);
        S1[lh] += __shfl_xor(S1[lh], off);
      }
    }
    if (ms == 0) {
      bf16* o = att_st + ((size_t)((b * 11 + ty) * N_ + n)) * C_;
#pragma unroll
      for (int lh = 0; lh < 2; ++lh) {
        int h = hg * 2 + lh;
        float inv = 1.f / Sp[lh];
#pragma unroll
        for (int d = 0; d < 8; ++d)
          o[h * 8 + d] = __float2bfloat16(
              (S0[lh] * Vw[lh][0][d] + S1[lh] * Vw[lh][1][d] + Sp[lh] * Vw[lh][2][d]) * inv);
      }
    }
  }
}

// ---------------- K1: spatial4 + temporal + pack (LDS = 6.9 KB) ------------
#define SP_BLKS 528
#define TMP_BLKS 127
#define PK_BLKS 534
__global__ __launch_bounds__(832) void k_phase1(
    const void* x,
    const void* Wq_t, const void* Wk_t, const void* Wv_t,
    const void* bq_t, const void* bk_t, const void* bv_t,
    const void* Wq_st, const void* Wk_st, const void* Wv_st,
    const void* bq_st, const void* bk_st, const void* bv_st,
    const void* xwz, const void* xwr, const void* xwh,
    const void* lwz, const void* lwr, const void* lwh,
    const void* Wpt, const void* Wps,
    bf16* att_t, bf16* att_st, bf16* pwb) {
  __shared__ float2 xs[N_];
  __shared__ float M[2][9];
  __shared__ float Vw[2][3][D_];
  int f32 = detect_f32(x);
  int bx = blockIdx.x;
  if (bx < SP_BLKS) {
    int tile = bx % 8, ty = (bx / 8) % 11, zz = bx / 88;
    int b = zz / 3, hg = zz % 3;
    if (f32)
      spatial4_body<float>(xs, M, Vw, tile, ty, b, hg,
                           (const float*)x, (const float*)Wq_st, (const float*)Wk_st,
                           (const float*)Wv_st, (const float*)bq_st, (const float*)bk_st,
                           (const float*)bv_st, att_st);
    else
      spatial4_body<bf16>(xs, M, Vw, tile, ty, b, hg,
                          (const bf16*)x, (const bf16*)Wq_st, (const bf16*)Wk_st,
                          (const bf16*)Wv_st, (const bf16*)bq_st, (const bf16*)bk_st,
                          (const bf16*)bv_st, att_st);
  } else if (bx < SP_BLKS + TMP_BLKS) {
    int gid = (bx - SP_BLKS) * 832 + threadIdx.x;
    if (f32)
      temporal_body<float>(gid, (const float*)x, (const float*)Wq_t, (const float*)Wk_t,
                           (const float*)Wv_t, (const float*)bq_t, (const float*)bk_t,
                           (const float*)bv_t, att_t);
    else
      temporal_body<bf16>(gid, (const bf16*)x, (const bf16*)Wq_t, (const bf16*)Wk_t,
                          (const bf16*)Wv_t, (const bf16*)bq_t, (const bf16*)bk_t,
                          (const bf16*)bv_t, att_t);
  } else {
    int gid = (bx - SP_BLKS - TMP_BLKS) * 832 + threadIdx.x;
    if (f32)
      pack_body<float>(gid, (const float*)xwz, (const float*)xwr, (const float*)xwh,
                       (const float*)lwz, (const float*)lwr, (const float*)lwh,
                       (const float*)Wpt, (const float*)Wps, pwb);
    else
      pack_body<bf16>(gid, (const bf16*)xwz, (const bf16*)xwr, (const bf16*)xwh,
                      (const bf16*)lwz, (const bf16*)lwr, (const bf16*)lwh,
                      (const bf16*)Wpt, (const bf16*)Wps, pwb);
  }
}

// ---------------- projx body (MFMA, pre-packed B-fragments) ----------------
template <typename TI>
__device__ __forceinline__ void projx2_body(
    unsigned short (*rawT)[72], unsigned short (*rawS)[72], unsigned short (*catS)[104],
    int tile, int ty, int b,
    const bf16* att_t, const bf16* att_st,
    const unsigned short* pwp, const unsigned short* pwx,
    const TI* bpt, const TI* bps,
    const TI* xbz, const TI* xbr, const TI* xbh,
    bf16* xfrag) {
  int t = ty + 1;
  int tid = threadIdx.x;
  int wv = tid >> 6, l = tid & 63;
  int cg = l >> 4, cl = l & 15;

  for (int e = tid; e < 64 * 72; e += 192) {
    int rr = e / 72, c = e % 72;
    int n = tile * 64 + rr; if (n > 799) n = 799;
    size_t base = ((size_t)((b * 11 + ty) * N_ + n)) * C_;
    rawT[rr][c] = (c < 48) ? __bfloat16_as_ushort(att_t[base + c]) : (unsigned short)0;
    rawS[rr][c] = (c < 48) ? __bfloat16_as_ushort(att_st[base + c]) : (unsigned short)0;
  }
  __syncthreads();
#pragma unroll
  for (int q = 0; q < 2; ++q) {
    int nt = 2 * wv + q;
    int half = nt / 3;
    int ncol = (nt - half * 3) * 16 + cl;
    float bias = half ? ldc(bps, ncol) : ldc(bpt, ncol);
    s8b Bf0 = *(const s8b*)(pwp + (nt * 2 + 0) * 512 + l * 8);
    s8b Bf1 = *(const s8b*)(pwp + (nt * 2 + 1) * 512 + l * 8);
    unsigned short (*raw)[72] = half ? rawS : rawT;
#pragma unroll
    for (int mt = 0; mt < 4; ++mt) {
      s8b A0 = *(const s8b*)&raw[mt * 16 + cl][cg * 8];
      s8b A1 = *(const s8b*)&raw[mt * 16 + cl][32 + cg * 8];
      f4 acc = {bias, bias, bias, bias};
      acc = __builtin_amdgcn_mfma_f32_16x16x32_bf16(A0, Bf0, acc, 0, 0, 0);
      acc = __builtin_amdgcn_mfma_f32_16x16x32_bf16(A1, Bf1, acc, 0, 0, 0);
#pragma unroll
      for (int r = 0; r < 4; ++r)
        catS[mt * 16 + cg * 4 + r][nt * 16 + cl] = f2u(acc[r]);
    }
  }
  __syncthreads();
#pragma unroll
  for (int q = 0; q < 3; ++q) {
    int nt = 3 * wv + q;
    int g = nt / 3;
    int jj = (nt - g * 3) * 16 + cl;
    const TI* bx = (g == 0) ? xbz : (g == 1) ? xbr : xbh;
    s8b Bf[3];
#pragma unroll
    for (int c = 0; c < 3; ++c)
      Bf[c] = *(const s8b*)(pwx + (((size_t)ty * 9 + nt) * 3 + c) * 512 + l * 8);
#pragma unroll
    for (int mt = 0; mt < 4; ++mt) {
      int nbase = tile * 64 + mt * 16;
      if (nbase >= 800) continue;
      s8b A0 = *(const s8b*)&catS[mt * 16 + cl][cg * 8];
      s8b A1 = *(const s8b*)&catS[mt * 16 + cl][32 + cg * 8];
      s8b A2 = *(const s8b*)&catS[mt * 16 + cl][64 + cg * 8];
      f4 acc;
#pragma unroll
      for (int r = 0; r < 4; ++r)
        acc[r] = ldc(bx, ((size_t)t * N_ + (nbase + cg * 4 + r)) * C_ + jj);
      acc = __builtin_amdgcn_mfma_f32_16x16x32_bf16(A0, Bf[0], acc, 0, 0, 0);
      acc = __builtin_amdgcn_mfma_f32_16x16x32_bf16(A1, Bf[1], acc, 0, 0, 0);
      acc = __builtin_amdgcn_mfma_f32_16x16x32_bf16(A2, Bf[2], acc, 0, 0, 0);
      int grp = b * 50 + tile * 4 + mt;
      size_t idx = ((((size_t)grp * 21 + ty) * 9 + nt) * 64 + l) * 4;
      ushort4 u;
      u.x = f2u(acc[0]); u.y = f2u(acc[1]); u.z = f2u(acc[2]); u.w = f2u(acc[3]);
      *(ushort4*)((unsigned short*)xfrag + idx) = u;
    }
  }
}

// ---------------- convx body (pre-packed B-fragments) ----------------------
template <typename TI>
__device__ __forceinline__ void convx5_body(
    float (*tpw)[KW_][2], float (*cw)[KW_][48], unsigned short (*preS)[72],
    int tile, int t, int b,
    const TI* x, const TI* T,
    const TI* conv1_w, const TI* conv1_b,
    const unsigned short* pwl,
    const TI* lbz, const TI* lbr, const TI* lbh,
    bf16* xfrag) {
  int tid = threadIdx.x;
  int wv = tid >> 6, l = tid & 63;
  int cg = l >> 4, cl = l & 15;
  int rw = tid / 12, jl = tid % 12;

#pragma unroll 7
  for (int p = 0; p < 7; ++p) {
    int e = tid + p * 192;
    int f = e / (KW_ * 48), rem = e % (KW_ * 48), k = rem / 48, c = rem % 48;
    cw[f][k][c] = ldc(conv1_w, (c * F_ + f) * KW_ + k);
  }
#pragma unroll 10
  for (int p = 0; p < 10; ++p) {
    int e = tid + p * 192;
    if (e < 64 * KW_ * 2) {
      int rr = e / (KW_ * 2), rem = e % (KW_ * 2), k = rem / 2, f = rem % 2;
      int n = tile * 64 + rr; if (n > 799) n = 799;
      int tau = t + k;
      float v;
      if (tau < TIN_) v = ldc(x, ((size_t)(b * TIN_ + tau) * N_ + n) * F_ + f);
      else if (tau < TIN_ + TP_) v = (f == 0) ? 0.f : ldc(T, (size_t)(b * TP_ + (tau - TIN_)) * N_ + n);
      else v = ldc(x, ((size_t)(b * TIN_ + 0) * N_ + n) * F_ + f);
      tpw[rr][k][f] = v;
    }
  }
  for (int e = tid; e < 64 * 24; e += 192)
    preS[e / 24][48 + e % 24] = 0;
  __syncthreads();
  {
    int c0 = jl * 4;
    float acc[4][4];
#pragma unroll
    for (int qq = 0; qq < 4; ++qq)
#pragma unroll
      for (int m = 0; m < 4; ++m) acc[qq][m] = ldc(conv1_b, c0 + m);
#pragma unroll
    for (int f = 0; f < 2; ++f)
      for (int k = 0; k < KW_; ++k) {
        const float4 w4 = *(const float4*)&cw[f][k][c0];
        float wvv[4] = {w4.x, w4.y, w4.z, w4.w};
#pragma unroll
        for (int qq = 0; qq < 4; ++qq) {
          float tv = tpw[rw * 4 + qq][k][f];
#pragma unroll
          for (int m = 0; m < 4; ++m) acc[qq][m] += tv * wvv[m];
        }
      }
#pragma unroll
    for (int qq = 0; qq < 4; ++qq)
#pragma unroll
      for (int m = 0; m < 4; ++m)
        preS[rw * 4 + qq][c0 + m] = f2u(acc[qq][m]);
  }
  __syncthreads();
#pragma unroll
  for (int q = 0; q < 3; ++q) {
    int nt = 3 * wv + q;
    int g = nt / 3;
    int jj = (nt - g * 3) * 16 + cl;
    const TI* bl = (g == 0) ? lbz : (g == 1) ? lbr : lbh;
    s8b Bf0 = *(const s8b*)(pwl + (((size_t)t * 9 + nt) * 2 + 0) * 512 + l * 8);
    s8b Bf1 = *(const s8b*)(pwl + (((size_t)t * 9 + nt) * 2 + 1) * 512 + l * 8);
#pragma unroll
    for (int mt = 0; mt < 4; ++mt) {
      int nbase = tile * 64 + mt * 16;
      if (nbase >= 800) continue;
      s8b A0 = *(const s8b*)&preS[mt * 16 + cl][cg * 8];
      s8b A1 = *(const s8b*)&preS[mt * 16 + cl][32 + cg * 8];
      f4 acc;
#pragma unroll
      for (int r = 0; r < 4; ++r)
        acc[r] = ldc(bl, ((size_t)t * N_ + (nbase + cg * 4 + r)) * C_ + jj);
      acc = __builtin_amdgcn_mfma_f32_16x16x32_bf16(A0, Bf0, acc, 0, 0, 0);
      acc = __builtin_amdgcn_mfma_f32_16x16x32_bf16(A1, Bf1, acc, 0, 0, 0);
      int grp = b * 50 + tile * 4 + mt;
      size_t idx = ((((size_t)grp * 21 + (11 + t)) * 9 + nt) * 64 + l) * 4;
      ushort4 u;
      u.x = f2u(acc[0]); u.y = f2u(acc[1]); u.z = f2u(acc[2]); u.w = f2u(acc[3]);
      *(ushort4*)((unsigned short*)xfrag + idx) = u;
    }
  }
}

// ---------------- K2: projx (bx<286) + convx (bx>=286), 192 thr ------------
#define PJ_BLKS 286
#define CV_BLKS 260
__global__ __launch_bounds__(192) void k_xc(
    const bf16* att_t, const bf16* att_st,
    const void* bpt, const void* bps,
    const void* xbz, const void* xbr, const void* xbh,
    const void* x, const void* T, const void* cw_, const void* cb,
    const void* lbz, const void* lbr, const void* lbh,
    const bf16* pwb, bf16* xfrag) {
  __shared__ __align__(16) char smem[31744];
  int f32 = detect_f32(x);
  int bx = blockIdx.x;
  const unsigned short* pwx = (const unsigned short*)(pwb + PACK_GRU_TOT);
  const unsigned short* pwp = (const unsigned short*)(pwb + PACK_GRU_TOT + PACK_PWX_TOT);
  const unsigned short* pwl = (const unsigned short*)(pwb + PACK_GRU_TOT + PACK_PWX_TOT + PACK_PWP_TOT);
  if (bx < PJ_BLKS) {
    int tile = bx % 13, ty = (bx / 13) % 11, b = bx / 143;
    auto rawT = (unsigned short(*)[72])smem;
    auto rawS = (unsigned short(*)[72])(smem + 9216);
    auto catS = (unsigned short(*)[104])(smem + 18432);
    if (f32)
      projx2_body<float>(rawT, rawS, catS, tile, ty, b, att_t, att_st, pwp, pwx,
                         (const float*)bpt, (const float*)bps,
                         (const float*)xbz, (const float*)xbr, (const float*)xbh, xfrag);
    else
      projx2_body<bf16>(rawT, rawS, catS, tile, ty, b, att_t, att_st, pwp, pwx,
                        (const bf16*)bpt, (const bf16*)bps,
                        (const bf16*)xbz, (const bf16*)xbr, (const bf16*)xbh, xfrag);
  } else {
    int cblk = bx - PJ_BLKS;
    int tile = cblk % 13, t = (cblk / 13) % 10, b = cblk / 130;
    auto tpw  = (float(*)[KW_][2])smem;
    auto cw   = (float(*)[KW_][48])(smem + 7168);
    auto preS = (unsigned short(*)[72])(smem + 12544);
    if (f32)
      convx5_body<float>(tpw, cw, preS, tile, t, b,
                         (const float*)x, (const float*)T, (const float*)cw_, (const float*)cb,
                         pwl, (const float*)lbz, (const float*)lbr, (const float*)lbh, xfrag);
    else
      convx5_body<bf16>(tpw, cw, preS, tile, t, b,
                        (const bf16*)x, (const bf16*)T, (const bf16*)cw_, (const bf16*)cb,
                        pwl, (const bf16*)lbz, (const bf16*)lbr, (const bf16*)lbh, xfrag);
  }
}

// ---------------- K3: MFMA GRU v12 — register dbuf + asm-pinned prefetch ---
template <bool PF, typename TO>
__device__ __forceinline__ void gru_step12(
    int step, int l, int cg, int cl, int b, int n0,
    s8b (&Wzc)[3][2], s8b (&Wrc)[3][2], s8b (&Whc)[3][2], ushort4 (&cxc)[9],
    s8b (&Wzn)[3][2], s8b (&Wrn)[3][2], s8b (&Whn)[3][2], ushort4 (&cxn)[9],
    const unsigned short* pwb, const unsigned short* xg,
    unsigned short* hT, unsigned short* rhT,
    float (&ho)[3][4], const s8b& WoB0, const s8b& WoB1, float bo, TO* out) {
  s8b hA0 = *(const s8b*)&hT[cl * 72 + cg * 8];
  s8b hA1 = *(const s8b*)&hT[cl * 72 + 32 + cg * 8];
  if (step >= 12) {
    f4 oacc = {bo, bo, bo, bo};
    oacc = __builtin_amdgcn_mfma_f32_16x16x32_bf16(hA0, WoB0, oacc, 0, 0, 0);
    oacc = __builtin_amdgcn_mfma_f32_16x16x32_bf16(hA1, WoB1, oacc, 0, 0, 0);
    if (cl == 0) {
      int t = step - 12;
#pragma unroll
      for (int r = 0; r < 4; ++r)
        sto(out, ((size_t)b * TP_ + t) * N_ + n0 + cg * 4 + r, oacc[r]);
    }
  }
  if (PF) {
    const unsigned short* pb = pwb + (size_t)(step + 1) * 9216 + (size_t)l * 8;
#pragma unroll
    for (int nt = 0; nt < 3; ++nt)
#pragma unroll
      for (int c = 0; c < 2; ++c) {
        Wzn[nt][c] = *(const s8b*)(pb + 0 * 3072 + nt * 1024 + c * 512);
        Wrn[nt][c] = *(const s8b*)(pb + 1 * 3072 + nt * 1024 + c * 512);
        Whn[nt][c] = *(const s8b*)(pb + 2 * 3072 + nt * 1024 + c * 512);
      }
    const unsigned short* xsrc = xg + (size_t)(step + 1) * 2304 + (size_t)l * 4;
#pragma unroll
    for (int gn = 0; gn < 9; ++gn)
      cxn[gn] = *(const ushort4*)(xsrc + gn * 256);
  }
  f4 az[3], ar[3];
#pragma unroll
  for (int nt = 0; nt < 3; ++nt) {
    f4 cz = {bfu(cxc[nt].x), bfu(cxc[nt].y), bfu(cxc[nt].z), bfu(cxc[nt].w)};
    cz = __builtin_amdgcn_mfma_f32_16x16x32_bf16(hA0, Wzc[nt][0], cz, 0, 0, 0);
    cz = __builtin_amdgcn_mfma_f32_16x16x32_bf16(hA1, Wzc[nt][1], cz, 0, 0, 0);
    az[nt] = cz;
    f4 cr = {bfu(cxc[3 + nt].x), bfu(cxc[3 + nt].y), bfu(cxc[3 + nt].z), bfu(cxc[3 + nt].w)};
    cr = __builtin_amdgcn_mfma_f32_16x16x32_bf16(hA0, Wrc[nt][0], cr, 0, 0, 0);
    cr = __builtin_amdgcn_mfma_f32_16x16x32_bf16(hA1, Wrc[nt][1], cr, 0, 0, 0);
    ar[nt] = cr;
  }
  float z[3][4];
#pragma unroll
  for (int nt = 0; nt < 3; ++nt)
#pragma unroll
    for (int r = 0; r < 4; ++r) {
      z[nt][r] = sigm(az[nt][r]);
      float rv = sigm(ar[nt][r]) * ho[nt][r];
      rhT[(cg * 4 + r) * 72 + nt * 16 + cl] = f2u(rv);
    }
  asm volatile("" ::: "memory");
  s8b rA0 = *(const s8b*)&rhT[cl * 72 + cg * 8];
  s8b rA1 = *(const s8b*)&rhT[cl * 72 + 32 + cg * 8];
  f4 ah[3];
#pragma unroll
  for (int nt = 0; nt < 3; ++nt) {
    f4 ch = {bfu(cxc[6 + nt].x), bfu(cxc[6 + nt].y), bfu(cxc[6 + nt].z), bfu(cxc[6 + nt].w)};
    ch = __builtin_amdgcn_mfma_f32_16x16x32_bf16(rA0, Whc[nt][0], ch, 0, 0, 0);
    ch = __builtin_amdgcn_mfma_f32_16x16x32_bf16(rA1, Whc[nt][1], ch, 0, 0, 0);
    ah[nt] = ch;
  }
#pragma unroll
  for (int nt = 0; nt < 3; ++nt)
#pragma unroll
    for (int r = 0; r < 4; ++r) {
      float hn = (1.f - z[nt][r]) * ho[nt][r] + z[nt][r] * tanh_(ah[nt][r]);
      ho[nt][r] = hn;
      hT[(cg * 4 + r) * 72 + nt * 16 + cl] = f2u(hn);
    }
  asm volatile("" ::: "memory");
  if (PF) {
#pragma unroll
    for (int nt = 0; nt < 3; ++nt)
#pragma unroll
      for (int c = 0; c < 2; ++c) {
        PIN(Wzn[nt][c]); PIN(Wrn[nt][c]); PIN(Whn[nt][c]);
      }
#pragma unroll
    for (int gn = 0; gn < 9; ++gn) PIN(cxn[gn]);
  }
}

template <typename TI, typename TO>
__device__ __forceinline__ void gru12_body(
    unsigned short* hT, unsigned short* rhT,
    const unsigned short* xfrag, const unsigned short* pwb,
    const TI* Wout, const TI* bout, TO* out) {
  int l = threadIdx.x;          // 64
  int cg = l >> 4, cl = l & 15;
  int blk = blockIdx.x;
  int b = blk / 50;
  int n0 = (blk % 50) * 16;

  for (int e = l; e < 1152; e += 64) { hT[e] = 0; rhT[e] = 0; }
  float bo = ldc(bout, 0);
  s8b WoB0, WoB1;
#pragma unroll
  for (int j = 0; j < 8; ++j) {
    int k0 = cg * 8 + j;
    int k1 = 32 + cg * 8 + j;
    WoB0[j] = (cl == 0) ? (short)f2u(ldc(Wout, k0)) : (short)0;
    WoB1[j] = (cl == 0 && k1 < 48) ? (short)f2u(ldc(Wout, k1)) : (short)0;
  }
  float ho[3][4];
#pragma unroll
  for (int nt = 0; nt < 3; ++nt)
#pragma unroll
    for (int r = 0; r < 4; ++r) ho[nt][r] = 0.f;

  const unsigned short* xg = xfrag + (size_t)blk * 48384;
  s8b WzA[3][2], WrA[3][2], WhA[3][2];
  s8b WzB[3][2], WrB[3][2], WhB[3][2];
  ushort4 cxA[9], cxB[9];
  {
    const unsigned short* pb = pwb + (size_t)l * 8;
#pragma unroll
    for (int nt = 0; nt < 3; ++nt)
#pragma unroll
      for (int c = 0; c < 2; ++c) {
        WzA[nt][c] = *(const s8b*)(pb + 0 * 3072 + nt * 1024 + c * 512);
        WrA[nt][c] = *(const s8b*)(pb + 1 * 3072 + nt * 1024 + c * 512);
        WhA[nt][c] = *(const s8b*)(pb + 2 * 3072 + nt * 1024 + c * 512);
      }
#pragma unroll
    for (int gn = 0; gn < 9; ++gn)
      cxA[gn] = *(const ushort4*)(xg + gn * 256 + l * 4);
  }
  asm volatile("" ::: "memory");

#pragma unroll 1
  for (int s2 = 0; s2 < 10; ++s2) {
    gru_step12<true>(2 * s2, l, cg, cl, b, n0,
                     WzA, WrA, WhA, cxA, WzB, WrB, WhB, cxB,
                     pwb, xg, hT, rhT, ho, WoB0, WoB1, bo, out);
    gru_step12<true>(2 * s2 + 1, l, cg, cl, b, n0,
                     WzB, WrB, WhB, cxB, WzA, WrA, WhA, cxA,
                     pwb, xg, hT, rhT, ho, WoB0, WoB1, bo, out);
  }
  gru_step12<false>(20, l, cg, cl, b, n0,
                    WzA, WrA, WhA, cxA, WzB, WrB, WhB, cxB,
                    pwb, xg, hT, rhT, ho, WoB0, WoB1, bo, out);
  {
    s8b hA0 = *(const s8b*)&hT[cl * 72 + cg * 8];
    s8b hA1 = *(const s8b*)&hT[cl * 72 + 32 + cg * 8];
    f4 oacc = {bo, bo, bo, bo};
    oacc = __builtin_amdgcn_mfma_f32_16x16x32_bf16(hA0, WoB0, oacc, 0, 0, 0);
    oacc = __builtin_amdgcn_mfma_f32_16x16x32_bf16(hA1, WoB1, oacc, 0, 0, 0);
    if (cl == 0) {
#pragma unroll
      for (int r = 0; r < 4; ++r)
        sto(out, ((size_t)b * TP_ + 9) * N_ + n0 + cg * 4 + r, oacc[r]);
    }
  }
}
__global__ __launch_bounds__(64, 1) void k_gru12(
    const void* xin, const bf16* xfrag, const bf16* pwb,
    const void* Wout, const void* bout, void* out) {
  __shared__ alignas(16) unsigned short hT[1152];
  __shared__ alignas(16) unsigned short rhT[1152];
  int f32 = detect_f32(xin);
  if (f32)
    gru12_body<float, float>(hT, rhT,
                             (const unsigned short*)xfrag, (const unsigned short*)pwb,
                             (const float*)Wout, (const float*)bout, (float*)out);
  else
    gru12_body<bf16, bf16>(hT, rhT,
                           (const unsigned short*)xfrag, (const unsigned short*)pwb,
                           (const bf16*)Wout, (const bf16*)bout, (bf16*)out);
}

// ---------------------------------------------------------------------------
extern "C" void kernel_launch(void* const* d_in, const int* in_sizes, int n_in,
                              void* d_out, int out_size, void* d_ws, size_t ws_size,
                              hipStream_t stream) {
  (void)in_sizes; (void)n_in; (void)out_size; (void)ws_size;
  const void* x       = d_in[0];
  const void* T       = d_in[1];
  const void* Wq_t    = d_in[3];
  const void* Wk_t    = d_in[4];
  const void* Wv_t    = d_in[5];
  const void* Wq_st   = d_in[6];
  const void* Wk_st   = d_in[7];
  const void* Wv_st   = d_in[8];
  const void* bq_t    = d_in[9];
  const void* bk_t    = d_in[10];
  const void* bv_t    = d_in[11];
  const void* bq_st   = d_in[12];
  const void* bk_st   = d_in[13];
  const void* bv_st   = d_in[14];
  const void* conv1_w = d_in[15];
  const void* conv1_b = d_in[16];
  const void* Wproj_t = d_in[17];
  const void* bproj_t = d_in[18];
  const void* Wproj_st= d_in[19];
  const void* bproj_st= d_in[20];
  const void* xhr_wz  = d_in[21];
  const void* xhr_wr  = d_in[22];
  const void* xhr_wh  = d_in[23];
  const void* xhr_bz  = d_in[24];
  const void* xhr_br  = d_in[25];
  const void* xhr_bh  = d_in[26];
  const void* last_wz = d_in[27];
  const void* last_wr = d_in[28];
  const void* last_wh = d_in[29];
  const void* last_bz = d_in[30];
  const void* last_br = d_in[31];
  const void* last_bh = d_in[32];
  const void* Wout    = d_in[33];
  const void* bout    = d_in[34];

  // ws layout (~13.9 MB; 14.75 MB proven safe earlier)
  char* wsb = (char*)d_ws;
  bf16* att_t  = (bf16*)(wsb + 256);                     // 2*11*800*48
  bf16* att_st = att_t + (size_t)2 * 11 * 800 * 48;
  bf16* xfrag  = att_st + (size_t)2 * 11 * 800 * 48;     // 100*21*9*64*4 elems
  bf16* pwb    = xfrag + (size_t)100 * 21 * 9 * 64 * 4;  // PACK_TOT elems

  k_phase1<<<SP_BLKS + TMP_BLKS + PK_BLKS, 832, 0, stream>>>(
      x, Wq_t, Wk_t, Wv_t, bq_t, bk_t, bv_t,
      Wq_st, Wk_st, Wv_st, bq_st, bk_st, bv_st,
      xhr_wz, xhr_wr, xhr_wh, last_wz, last_wr, last_wh,
      Wproj_t, Wproj_st,
      att_t, att_st, pwb);
  k_xc<<<PJ_BLKS + CV_BLKS, 192, 0, stream>>>(
      att_t, att_st, bproj_t, bproj_st,
      xhr_bz, xhr_br, xhr_bh,
      x, T, conv1_w, conv1_b, last_bz, last_br, last_bh,
      pwb, xfrag);
  k_gru12<<<100, 64, 0, stream>>>(
      x, xfrag, pwb, Wout, bout, d_out);
}

// Round 21
// 97.640 us; speedup vs baseline: 1.3355x; 1.0009x over previous
//
#include <hip/hip_runtime.h>
#include <hip/hip_bf16.h>

typedef __hip_bfloat16 bf16;
typedef __attribute__((ext_vector_type(8))) short s8b;   // 8 bf16 (4 VGPR)
typedef __attribute__((ext_vector_type(4))) float f4;    // MFMA C/D

#define B_ 2
#define TIN_ 12
#define N_ 800
#define F_ 2
#define H_ 6
#define D_ 8
#define C_ 48
#define TP_ 10
#define KW_ 14
#define SCALE 0.35355339059327373f  // 1/sqrt(8)
#define LOG2E 1.4426950408889634f

#define PIN(v) asm volatile("" :: "v"(v))

// packed-weight region sizes (elements)
#define PACK_GRU_TOT (21 * 9216)
#define PACK_PWX_TOT (11 * 9 * 3 * 512)
#define PACK_PWP_TOT (6 * 2 * 512)
#define PACK_PWL_TOT (10 * 9 * 2 * 512)
#define PACK_TOT (PACK_GRU_TOT + PACK_PWX_TOT + PACK_PWP_TOT + PACK_PWL_TOT)

__device__ __forceinline__ float sigm(float x) { return 1.0f / (1.0f + __expf(-x)); }
__device__ __forceinline__ float tanh_(float x) {
  float e = __expf(-2.0f * x);
  return 2.0f / (1.0f + e) - 1.0f;
}
__device__ __forceinline__ float exp2_(float x) { return __builtin_amdgcn_exp2f(x); }
__device__ __forceinline__ float bfu(unsigned short u) {
  return __uint_as_float((unsigned)u << 16);
}
__device__ __forceinline__ unsigned short f2u(float v) {
  return __bfloat16_as_ushort(__float2bfloat16(v));
}
__device__ __forceinline__ float ldc(const float* p, size_t i) { return p[i]; }
__device__ __forceinline__ float ldc(const bf16* p, size_t i) { return __bfloat162float(p[i]); }
__device__ __forceinline__ void sto(float* p, size_t i, float v) { p[i] = v; }
__device__ __forceinline__ void sto(bf16* p, size_t i, float v) { p[i] = __float2bfloat16(v); }
__device__ __forceinline__ int detect_f32(const void* xv) {
  const unsigned int* xw = (const unsigned int*)xv;
  unsigned int w = xw[threadIdx.x & 63];
  int e = (w >> 7) & 0xFF;
  int bad = ((e >= 1 && e < 96) || (e > 150)) ? 1 : 0;
  unsigned long long m = __ballot(bad);
  return (__popcll(m) >= 16) ? 1 : 0;
}

// ---------------- pack body: ALL MFMA B-fragments --------------------------
template <typename TI>
__device__ __forceinline__ void pack_body(
    int gid, const TI* xwz, const TI* xwr, const TI* xwh,
    const TI* lwz, const TI* lwr, const TI* lwh,
    const TI* Wpt, const TI* Wps, bf16* pwb) {
  if (gid >= PACK_TOT) return;
  float v = 0.f;
  if (gid < PACK_GRU_TOT) {
    int step = gid / 9216, r = gid % 9216;
    int g = r / 3072;  r %= 3072;
    int nt = r / 1024; r %= 1024;
    int c = r / 512;   r %= 512;
    int lane = r / 8, j = r % 8;
    int k = 32 * c + (lane >> 4) * 8 + j;
    int n = nt * 16 + (lane & 15);
    if (k < 48) {
      if (step < 11) {
        int t = step + 1;
        const TI* w = (g == 0) ? xwz : (g == 1) ? xwr : xwh;
        v = ldc(w, ((size_t)t * 144 + 96 + k) * 48 + n);
      } else {
        int t = step - 11;
        const TI* w = (g == 0) ? lwz : (g == 1) ? lwr : lwh;
        v = ldc(w, ((size_t)t * 96 + 48 + k) * 48 + n);
      }
    }
  } else {
    int e2 = gid - PACK_GRU_TOT;
    if (e2 < PACK_PWX_TOT) {
      int j = e2 & 7, lane = (e2 >> 3) & 63;
      int c = (e2 >> 9) % 3, nt = (e2 / 1536) % 9, tt = e2 / 13824;
      int t = tt + 1;
      int k = c * 32 + (lane >> 4) * 8 + j;
      int g = nt / 3, jj = (nt - g * 3) * 16 + (lane & 15);
      const TI* w = (g == 0) ? xwz : (g == 1) ? xwr : xwh;
      v = ldc(w, ((size_t)t * 144 + k) * 48 + jj);
    } else {
      int e3 = e2 - PACK_PWX_TOT;
      if (e3 < PACK_PWP_TOT) {
        int j = e3 & 7, lane = (e3 >> 3) & 63;
        int c = (e3 >> 9) & 1, nt = e3 / 1024;
        int k = c * 32 + (lane >> 4) * 8 + j;
        int half = nt / 3, ncol = (nt - half * 3) * 16 + (lane & 15);
        if (k < 48)
          v = half ? ldc(Wps, (size_t)k * 48 + ncol) : ldc(Wpt, (size_t)k * 48 + ncol);
      } else {
        int e4 = e3 - PACK_PWP_TOT;
        int j = e4 & 7, lane = (e4 >> 3) & 63;
        int c = (e4 >> 9) & 1, nt = (e4 / 1024) % 9, t = e4 / 9216;
        int k = c * 32 + (lane >> 4) * 8 + j;
        int g = nt / 3, jj = (nt - g * 3) * 16 + (lane & 15);
        const TI* w = (g == 0) ? lwz : (g == 1) ? lwr : lwh;
        if (k < 48) v = ldc(w, ((size_t)t * 96 + k) * 48 + jj);
      }
    }
  }
  pwb[gid] = __float2bfloat16(v);
}

// ---------------- temporal body (per-element gid) --------------------------
template <typename TI>
__device__ __forceinline__ void temporal_body(
    int gid, const TI* x, const TI* Wq, const TI* Wk, const TI* Wv,
    const TI* bq, const TI* bk, const TI* bv, bf16* att_t) {
  const int total = B_ * (TIN_ - 1) * H_ * N_;
  if (gid >= total) return;
  int n = gid % N_;
  int r = gid / N_;
  int h = r % H_;  r /= H_;
  int t = (r % (TIN_ - 1)) + 1;
  int b = r / (TIN_ - 1);

  float wq[F_][D_], wk[F_][D_], wv[F_][D_], bqv[D_], bkv[D_], bvv[D_];
#pragma unroll
  for (int f = 0; f < F_; ++f)
#pragma unroll
    for (int d = 0; d < D_; ++d) {
      wq[f][d] = ldc(Wq, (h * F_ + f) * D_ + d);
      wk[f][d] = ldc(Wk, (h * F_ + f) * D_ + d);
      wv[f][d] = ldc(Wv, (h * F_ + f) * D_ + d);
    }
#pragma unroll
  for (int d = 0; d < D_; ++d) {
    bqv[d] = ldc(bq, h * D_ + d);
    bkv[d] = ldc(bk, h * D_ + d);
    bvv[d] = ldc(bv, h * D_ + d);
  }
  float xt0 = ldc(x, ((b * TIN_ + t) * N_ + n) * F_ + 0);
  float xt1 = ldc(x, ((b * TIN_ + t) * N_ + n) * F_ + 1);
  float q[D_];
#pragma unroll
  for (int d = 0; d < D_; ++d) q[d] = xt0 * wq[0][d] + xt1 * wq[1][d] + bqv[d];

  float sc[TIN_];
  float mx = -1e30f;
#pragma unroll
  for (int s = 0; s < TIN_; ++s) {
    float xs0 = ldc(x, ((b * TIN_ + s) * N_ + n) * F_ + 0);
    float xs1 = ldc(x, ((b * TIN_ + s) * N_ + n) * F_ + 1);
    float dot = 0.f;
#pragma unroll
    for (int d = 0; d < D_; ++d)
      dot += q[d] * (xs0 * wk[0][d] + xs1 * wk[1][d] + bkv[d]);
    dot *= SCALE;
    sc[s] = (s <= t) ? dot : -1e30f;
    mx = fmaxf(mx, sc[s]);
  }
  float sum = 0.f;
#pragma unroll
  for (int s = 0; s < TIN_; ++s) {
    float p = __expf(sc[s] - mx);
    sc[s] = p;
    sum += p;
  }
  float inv = 1.0f / sum;
  float acc[D_];
#pragma unroll
  for (int d = 0; d < D_; ++d) acc[d] = 0.f;
#pragma unroll
  for (int s = 0; s < TIN_; ++s) {
    float xs0 = ldc(x, ((b * TIN_ + s) * N_ + n) * F_ + 0);
    float xs1 = ldc(x, ((b * TIN_ + s) * N_ + n) * F_ + 1);
#pragma unroll
    for (int d = 0; d < D_; ++d)
      acc[d] += sc[s] * (xs0 * wv[0][d] + xs1 * wv[1][d] + bvv[d]);
  }
  bf16* o = att_t + ((size_t)((b * 11 + (t - 1)) * N_ + n)) * C_ + h * D_;
#pragma unroll
  for (int d = 0; d < D_; ++d) o[d] = __float2bfloat16(acc[d] * inv);
}

// ---------------- spatial4: rank-2, head-split, shfl-reduced ---------------
template <typename TI>
__device__ __forceinline__ void spatial4_body(
    float2* xs, float (*M)[9], float (*Vw)[3][D_],
    int tile, int ty, int b, int hg,
    const TI* x, const TI* Wq, const TI* Wk, const TI* Wv,
    const TI* bq, const TI* bk, const TI* bv, bf16* att_st) {
  int t = ty + 1;
  int tid = threadIdx.x;

  for (int m = tid; m < N_; m += 832)
    xs[m] = make_float2(ldc(x, ((b * TIN_ + t) * N_ + m) * F_ + 0),
                        ldc(x, ((b * TIN_ + t) * N_ + m) * F_ + 1));
  if (tid < 18) {
    int lh = tid / 9, e = tid % 9, a = e / 3, bb = e % 3;
    int h = hg * 2 + lh;
    float acc = 0.f;
    for (int d = 0; d < 8; ++d) {
      float qa = (a == 0) ? ldc(Wq, (h * 2 + 0) * 8 + d)
               : (a == 1) ? ldc(Wq, (h * 2 + 1) * 8 + d) : ldc(bq, h * 8 + d);
      float kb = (bb == 0) ? ldc(Wk, (h * 2 + 0) * 8 + d)
               : (bb == 1) ? ldc(Wk, (h * 2 + 1) * 8 + d) : ldc(bk, h * 8 + d);
      acc += qa * kb;
    }
    M[lh][e] = acc * SCALE * LOG2E;
  }
  if (tid >= 64 && tid < 64 + 48) {
    int e = tid - 64;
    int lh = e / 24, a = (e % 24) / 8, d = e % 8;
    int h = hg * 2 + lh;
    Vw[lh][a][d] = (a == 0) ? ldc(Wv, (h * 2 + 0) * 8 + d)
                 : (a == 1) ? ldc(Wv, (h * 2 + 1) * 8 + d) : ldc(bv, h * 8 + d);
  }
  __syncthreads();
  if (tid < 800) {
    int row = tid >> 3, ms = tid & 7;
    int n = tile * 100 + row;
    float x0 = xs[n].x, x1 = xs[n].y;
    float A[2], Bc[2];
#pragma unroll
    for (int lh = 0; lh < 2; ++lh) {
      A[lh]  = M[lh][0] * x0 + M[lh][3] * x1 + M[lh][6];
      Bc[lh] = M[lh][1] * x0 + M[lh][4] * x1 + M[lh][7];
    }
    float Sp[2] = {0, 0}, S0[2] = {0, 0}, S1[2] = {0, 0};
    for (int m = ms * 100; m < ms * 100 + 100; ++m) {
      float2 xm = xs[m];
#pragma unroll
      for (int lh = 0; lh < 2; ++lh) {
        float p = exp2_(A[lh] * xm.x + Bc[lh] * xm.y);
        Sp[lh] += p;
        S0[lh] += p * xm.x;
        S1[lh] += p * xm.y;
      }
    }
#pragma unroll
    for (int lh = 0; lh < 2; ++lh) {
#pragma unroll
      for (int off = 1; off < 8; off <<= 1) {
        Sp[lh] += __shfl_xor(Sp[lh], off);
        S0[lh] += __shfl_xor(S0[lh], off);
        S1[lh] += __shfl_xor(S1[lh], off);
      }
    }
    if (ms == 0) {
      bf16* o = att_st + ((size_t)((b * 11 + ty) * N_ + n)) * C_;
#pragma unroll
      for (int lh = 0; lh < 2; ++lh) {
        int h = hg * 2 + lh;
        float inv = 1.f / Sp[lh];
#pragma unroll
        for (int d = 0; d < 8; ++d)
          o[h * 8 + d] = __float2bfloat16(
              (S0[lh] * Vw[lh][0][d] + S1[lh] * Vw[lh][1][d] + Sp[lh] * Vw[lh][2][d]) * inv);
      }
    }
  }
}

// ---------------- K1: spatial4 + temporal + pack (LDS = 6.9 KB) ------------
#define SP_BLKS 528
#define TMP_BLKS 127
#define PK_BLKS 534
__global__ __launch_bounds__(832) void k_phase1(
    const void* x,
    const void* Wq_t, const void* Wk_t, const void* Wv_t,
    const void* bq_t, const void* bk_t, const void* bv_t,
    const void* Wq_st, const void* Wk_st, const void* Wv_st,
    const void* bq_st, const void* bk_st, const void* bv_st,
    const void* xwz, const void* xwr, const void* xwh,
    const void* lwz, const void* lwr, const void* lwh,
    const void* Wpt, const void* Wps,
    bf16* att_t, bf16* att_st, bf16* pwb) {
  __shared__ float2 xs[N_];
  __shared__ float M[2][9];
  __shared__ float Vw[2][3][D_];
  int f32 = detect_f32(x);
  int bx = blockIdx.x;
  if (bx < SP_BLKS) {
    int tile = bx % 8, ty = (bx / 8) % 11, zz = bx / 88;
    int b = zz / 3, hg = zz % 3;
    if (f32)
      spatial4_body<float>(xs, M, Vw, tile, ty, b, hg,
                           (const float*)x, (const float*)Wq_st, (const float*)Wk_st,
                           (const float*)Wv_st, (const float*)bq_st, (const float*)bk_st,
                           (const float*)bv_st, att_st);
    else
      spatial4_body<bf16>(xs, M, Vw, tile, ty, b, hg,
                          (const bf16*)x, (const bf16*)Wq_st, (const bf16*)Wk_st,
                          (const bf16*)Wv_st, (const bf16*)bq_st, (const bf16*)bk_st,
                          (const bf16*)bv_st, att_st);
  } else if (bx < SP_BLKS + TMP_BLKS) {
    int gid = (bx - SP_BLKS) * 832 + threadIdx.x;
    if (f32)
      temporal_body<float>(gid, (const float*)x, (const float*)Wq_t, (const float*)Wk_t,
                           (const float*)Wv_t, (const float*)bq_t, (const float*)bk_t,
                           (const float*)bv_t, att_t);
    else
      temporal_body<bf16>(gid, (const bf16*)x, (const bf16*)Wq_t, (const bf16*)Wk_t,
                          (const bf16*)Wv_t, (const bf16*)bq_t, (const bf16*)bk_t,
                          (const bf16*)bv_t, att_t);
  } else {
    int gid = (bx - SP_BLKS - TMP_BLKS) * 832 + threadIdx.x;
    if (f32)
      pack_body<float>(gid, (const float*)xwz, (const float*)xwr, (const float*)xwh,
                       (const float*)lwz, (const float*)lwr, (const float*)lwh,
                       (const float*)Wpt, (const float*)Wps, pwb);
    else
      pack_body<bf16>(gid, (const bf16*)xwz, (const bf16*)xwr, (const bf16*)xwh,
                      (const bf16*)lwz, (const bf16*)lwr, (const bf16*)lwh,
                      (const bf16*)Wpt, (const bf16*)Wps, pwb);
  }
}

// ---------------- projx body (MFMA, pre-packed B-fragments) ----------------
template <typename TI>
__device__ __forceinline__ void projx2_body(
    unsigned short (*rawT)[72], unsigned short (*rawS)[72], unsigned short (*catS)[104],
    int tile, int ty, int b,
    const bf16* att_t, const bf16* att_st,
    const unsigned short* pwp, const unsigned short* pwx,
    const TI* bpt, const TI* bps,
    const TI* xbz, const TI* xbr, const TI* xbh,
    bf16* xfrag) {
  int t = ty + 1;
  int tid = threadIdx.x;
  int wv = tid >> 6, l = tid & 63;
  int cg = l >> 4, cl = l & 15;

  for (int e = tid; e < 64 * 72; e += 192) {
    int rr = e / 72, c = e % 72;
    int n = tile * 64 + rr; if (n > 799) n = 799;
    size_t base = ((size_t)((b * 11 + ty) * N_ + n)) * C_;
    rawT[rr][c] = (c < 48) ? __bfloat16_as_ushort(att_t[base + c]) : (unsigned short)0;
    rawS[rr][c] = (c < 48) ? __bfloat16_as_ushort(att_st[base + c]) : (unsigned short)0;
  }
  __syncthreads();
#pragma unroll
  for (int q = 0; q < 2; ++q) {
    int nt = 2 * wv + q;
    int half = nt / 3;
    int ncol = (nt - half * 3) * 16 + cl;
    float bias = half ? ldc(bps, ncol) : ldc(bpt, ncol);
    s8b Bf0 = *(const s8b*)(pwp + (nt * 2 + 0) * 512 + l * 8);
    s8b Bf1 = *(const s8b*)(pwp + (nt * 2 + 1) * 512 + l * 8);
    unsigned short (*raw)[72] = half ? rawS : rawT;
#pragma unroll
    for (int mt = 0; mt < 4; ++mt) {
      s8b A0 = *(const s8b*)&raw[mt * 16 + cl][cg * 8];
      s8b A1 = *(const s8b*)&raw[mt * 16 + cl][32 + cg * 8];
      f4 acc = {bias, bias, bias, bias};
      acc = __builtin_amdgcn_mfma_f32_16x16x32_bf16(A0, Bf0, acc, 0, 0, 0);
      acc = __builtin_amdgcn_mfma_f32_16x16x32_bf16(A1, Bf1, acc, 0, 0, 0);
#pragma unroll
      for (int r = 0; r < 4; ++r)
        catS[mt * 16 + cg * 4 + r][nt * 16 + cl] = f2u(acc[r]);
    }
  }
  __syncthreads();
#pragma unroll
  for (int q = 0; q < 3; ++q) {
    int nt = 3 * wv + q;
    int g = nt / 3;
    int jj = (nt - g * 3) * 16 + cl;
    const TI* bx = (g == 0) ? xbz : (g == 1) ? xbr : xbh;
    s8b Bf[3];
#pragma unroll
    for (int c = 0; c < 3; ++c)
      Bf[c] = *(const s8b*)(pwx + (((size_t)ty * 9 + nt) * 3 + c) * 512 + l * 8);
#pragma unroll
    for (int mt = 0; mt < 4; ++mt) {
      int nbase = tile * 64 + mt * 16;
      if (nbase >= 800) continue;
      s8b A0 = *(const s8b*)&catS[mt * 16 + cl][cg * 8];
      s8b A1 = *(const s8b*)&catS[mt * 16 + cl][32 + cg * 8];
      s8b A2 = *(const s8b*)&catS[mt * 16 + cl][64 + cg * 8];
      f4 acc;
#pragma unroll
      for (int r = 0; r < 4; ++r)
        acc[r] = ldc(bx, ((size_t)t * N_ + (nbase + cg * 4 + r)) * C_ + jj);
      acc = __builtin_amdgcn_mfma_f32_16x16x32_bf16(A0, Bf[0], acc, 0, 0, 0);
      acc = __builtin_amdgcn_mfma_f32_16x16x32_bf16(A1, Bf[1], acc, 0, 0, 0);
      acc = __builtin_amdgcn_mfma_f32_16x16x32_bf16(A2, Bf[2], acc, 0, 0, 0);
      int grp = b * 50 + tile * 4 + mt;
      size_t idx = ((((size_t)grp * 21 + ty) * 9 + nt) * 64 + l) * 4;
      ushort4 u;
      u.x = f2u(acc[0]); u.y = f2u(acc[1]); u.z = f2u(acc[2]); u.w = f2u(acc[3]);
      *(ushort4*)((unsigned short*)xfrag + idx) = u;
    }
  }
}

// ---------------- convx body (pre-packed B-fragments) ----------------------
template <typename TI>
__device__ __forceinline__ void convx5_body(
    float (*tpw)[KW_][2], float (*cw)[KW_][48], unsigned short (*preS)[72],
    int tile, int t, int b,
    const TI* x, const TI* T,
    const TI* conv1_w, const TI* conv1_b,
    const unsigned short* pwl,
    const TI* lbz, const TI* lbr, const TI* lbh,
    bf16* xfrag) {
  int tid = threadIdx.x;
  int wv = tid >> 6, l = tid & 63;
  int cg = l >> 4, cl = l & 15;
  int rw = tid / 12, jl = tid % 12;

#pragma unroll 7
  for (int p = 0; p < 7; ++p) {
    int e = tid + p * 192;
    int f = e / (KW_ * 48), rem = e % (KW_ * 48), k = rem / 48, c = rem % 48;
    cw[f][k][c] = ldc(conv1_w, (c * F_ + f) * KW_ + k);
  }
#pragma unroll 10
  for (int p = 0; p < 10; ++p) {
    int e = tid + p * 192;
    if (e < 64 * KW_ * 2) {
      int rr = e / (KW_ * 2), rem = e % (KW_ * 2), k = rem / 2, f = rem % 2;
      int n = tile * 64 + rr; if (n > 799) n = 799;
      int tau = t + k;
      float v;
      if (tau < TIN_) v = ldc(x, ((size_t)(b * TIN_ + tau) * N_ + n) * F_ + f);
      else if (tau < TIN_ + TP_) v = (f == 0) ? 0.f : ldc(T, (size_t)(b * TP_ + (tau - TIN_)) * N_ + n);
      else v = ldc(x, ((size_t)(b * TIN_ + 0) * N_ + n) * F_ + f);
      tpw[rr][k][f] = v;
    }
  }
  for (int e = tid; e < 64 * 24; e += 192)
    preS[e / 24][48 + e % 24] = 0;
  __syncthreads();
  {
    int c0 = jl * 4;
    float acc[4][4];
#pragma unroll
    for (int qq = 0; qq < 4; ++qq)
#pragma unroll
      for (int m = 0; m < 4; ++m) acc[qq][m] = ldc(conv1_b, c0 + m);
#pragma unroll
    for (int f = 0; f < 2; ++f)
      for (int k = 0; k < KW_; ++k) {
        const float4 w4 = *(const float4*)&cw[f][k][c0];
        float wvv[4] = {w4.x, w4.y, w4.z, w4.w};
#pragma unroll
        for (int qq = 0; qq < 4; ++qq) {
          float tv = tpw[rw * 4 + qq][k][f];
#pragma unroll
          for (int m = 0; m < 4; ++m) acc[qq][m] += tv * wvv[m];
        }
      }
#pragma unroll
    for (int qq = 0; qq < 4; ++qq)
#pragma unroll
      for (int m = 0; m < 4; ++m)
        preS[rw * 4 + qq][c0 + m] = f2u(acc[qq][m]);
  }
  __syncthreads();
#pragma unroll
  for (int q = 0; q < 3; ++q) {
    int nt = 3 * wv + q;
    int g = nt / 3;
    int jj = (nt - g * 3) * 16 + cl;
    const TI* bl = (g == 0) ? lbz : (g == 1) ? lbr : lbh;
    s8b Bf0 = *(const s8b*)(pwl + (((size_t)t * 9 + nt) * 2 + 0) * 512 + l * 8);
    s8b Bf1 = *(const s8b*)(pwl + (((size_t)t * 9 + nt) * 2 + 1) * 512 + l * 8);
#pragma unroll
    for (int mt = 0; mt < 4; ++mt) {
      int nbase = tile * 64 + mt * 16;
      if (nbase >= 800) continue;
      s8b A0 = *(const s8b*)&preS[mt * 16 + cl][cg * 8];
      s8b A1 = *(const s8b*)&preS[mt * 16 + cl][32 + cg * 8];
      f4 acc;
#pragma unroll
      for (int r = 0; r < 4; ++r)
        acc[r] = ldc(bl, ((size_t)t * N_ + (nbase + cg * 4 + r)) * C_ + jj);
      acc = __builtin_amdgcn_mfma_f32_16x16x32_bf16(A0, Bf0, acc, 0, 0, 0);
      acc = __builtin_amdgcn_mfma_f32_16x16x32_bf16(A1, Bf1, acc, 0, 0, 0);
      int grp = b * 50 + tile * 4 + mt;
      size_t idx = ((((size_t)grp * 21 + (11 + t)) * 9 + nt) * 64 + l) * 4;
      ushort4 u;
      u.x = f2u(acc[0]); u.y = f2u(acc[1]); u.z = f2u(acc[2]); u.w = f2u(acc[3]);
      *(ushort4*)((unsigned short*)xfrag + idx) = u;
    }
  }
}

// ---------------- K2: projx (bx<286) + convx (bx>=286), 192 thr ------------
#define PJ_BLKS 286
#define CV_BLKS 260
__global__ __launch_bounds__(192) void k_xc(
    const bf16* att_t, const bf16* att_st,
    const void* bpt, const void* bps,
    const void* xbz, const void* xbr, const void* xbh,
    const void* x, const void* T, const void* cw_, const void* cb,
    const void* lbz, const void* lbr, const void* lbh,
    const bf16* pwb, bf16* xfrag) {
  __shared__ __align__(16) char smem[31744];
  int f32 = detect_f32(x);
  int bx = blockIdx.x;
  const unsigned short* pwx = (const unsigned short*)(pwb + PACK_GRU_TOT);
  const unsigned short* pwp = (const unsigned short*)(pwb + PACK_GRU_TOT + PACK_PWX_TOT);
  const unsigned short* pwl = (const unsigned short*)(pwb + PACK_GRU_TOT + PACK_PWX_TOT + PACK_PWP_TOT);
  if (bx < PJ_BLKS) {
    int tile = bx % 13, ty = (bx / 13) % 11, b = bx / 143;
    auto rawT = (unsigned short(*)[72])smem;
    auto rawS = (unsigned short(*)[72])(smem + 9216);
    auto catS = (unsigned short(*)[104])(smem + 18432);
    if (f32)
      projx2_body<float>(rawT, rawS, catS, tile, ty, b, att_t, att_st, pwp, pwx,
                         (const float*)bpt, (const float*)bps,
                         (const float*)xbz, (const float*)xbr, (const float*)xbh, xfrag);
    else
      projx2_body<bf16>(rawT, rawS, catS, tile, ty, b, att_t, att_st, pwp, pwx,
                        (const bf16*)bpt, (const bf16*)bps,
                        (const bf16*)xbz, (const bf16*)xbr, (const bf16*)xbh, xfrag);
  } else {
    int cblk = bx - PJ_BLKS;
    int tile = cblk % 13, t = (cblk / 13) % 10, b = cblk / 130;
    auto tpw  = (float(*)[KW_][2])smem;
    auto cw   = (float(*)[KW_][48])(smem + 7168);
    auto preS = (unsigned short(*)[72])(smem + 12544);
    if (f32)
      convx5_body<float>(tpw, cw, preS, tile, t, b,
                         (const float*)x, (const float*)T, (const float*)cw_, (const float*)cb,
                         pwl, (const float*)lbz, (const float*)lbr, (const float*)lbh, xfrag);
    else
      convx5_body<bf16>(tpw, cw, preS, tile, t, b,
                        (const bf16*)x, (const bf16*)T, (const bf16*)cw_, (const bf16*)cb,
                        pwl, (const bf16*)lbz, (const bf16*)lbr, (const bf16*)lbh, xfrag);
  }
}

// ---------------- K3: GRU v13 — dbuf + sched_barrier-pinned issue ----------
template <bool PF, typename TO>
__device__ __forceinline__ void gru_step13(
    int step, int l, int cg, int cl, int b, int n0,
    s8b (&Wzc)[3][2], s8b (&Wrc)[3][2], s8b (&Whc)[3][2], ushort4 (&cxc)[9],
    s8b (&Wzn)[3][2], s8b (&Wrn)[3][2], s8b (&Whn)[3][2], ushort4 (&cxn)[9],
    const unsigned short* pwb, const unsigned short* xg,
    unsigned short* hT, unsigned short* rhT,
    float (&ho)[3][4], const s8b& WoB0, const s8b& WoB1, float bo, TO* out) {
  s8b hA0 = *(const s8b*)&hT[cl * 72 + cg * 8];
  s8b hA1 = *(const s8b*)&hT[cl * 72 + 32 + cg * 8];
  if (step >= 12) {
    f4 oacc = {bo, bo, bo, bo};
    oacc = __builtin_amdgcn_mfma_f32_16x16x32_bf16(hA0, WoB0, oacc, 0, 0, 0);
    oacc = __builtin_amdgcn_mfma_f32_16x16x32_bf16(hA1, WoB1, oacc, 0, 0, 0);
    if (cl == 0) {
      int t = step - 12;
#pragma unroll
      for (int r = 0; r < 4; ++r)
        sto(out, ((size_t)b * TP_ + t) * N_ + n0 + cg * 4 + r, oacc[r]);
    }
  }
  if (PF) {  // issue next-step loads; sched_barrier pins issue point (no sinking)
    const unsigned short* pb = pwb + (size_t)(step + 1) * 9216 + (size_t)l * 8;
#pragma unroll
    for (int nt = 0; nt < 3; ++nt)
#pragma unroll
      for (int c = 0; c < 2; ++c) {
        Wzn[nt][c] = *(const s8b*)(pb + 0 * 3072 + nt * 1024 + c * 512);
        Wrn[nt][c] = *(const s8b*)(pb + 1 * 3072 + nt * 1024 + c * 512);
        Whn[nt][c] = *(const s8b*)(pb + 2 * 3072 + nt * 1024 + c * 512);
      }
    const unsigned short* xsrc = xg + (size_t)(step + 1) * 2304 + (size_t)l * 4;
#pragma unroll
    for (int gn = 0; gn < 9; ++gn)
      cxn[gn] = *(const ushort4*)(xsrc + gn * 256);
    __builtin_amdgcn_sched_barrier(0);
  }
  f4 az[3], ar[3];
#pragma unroll
  for (int nt = 0; nt < 3; ++nt) {
    f4 cz = {bfu(cxc[nt].x), bfu(cxc[nt].y), bfu(cxc[nt].z), bfu(cxc[nt].w)};
    cz = __builtin_amdgcn_mfma_f32_16x16x32_bf16(hA0, Wzc[nt][0], cz, 0, 0, 0);
    cz = __builtin_amdgcn_mfma_f32_16x16x32_bf16(hA1, Wzc[nt][1], cz, 0, 0, 0);
    az[nt] = cz;
    f4 cr = {bfu(cxc[3 + nt].x), bfu(cxc[3 + nt].y), bfu(cxc[3 + nt].z), bfu(cxc[3 + nt].w)};
    cr = __builtin_amdgcn_mfma_f32_16x16x32_bf16(hA0, Wrc[nt][0], cr, 0, 0, 0);
    cr = __builtin_amdgcn_mfma_f32_16x16x32_bf16(hA1, Wrc[nt][1], cr, 0, 0, 0);
    ar[nt] = cr;
  }
  float z[3][4];
#pragma unroll
  for (int nt = 0; nt < 3; ++nt)
#pragma unroll
    for (int r = 0; r < 4; ++r) {
      z[nt][r] = sigm(az[nt][r]);
      float rv = sigm(ar[nt][r]) * ho[nt][r];
      rhT[(cg * 4 + r) * 72 + nt * 16 + cl] = f2u(rv);
    }
  asm volatile("" ::: "memory");
  s8b rA0 = *(const s8b*)&rhT[cl * 72 + cg * 8];
  s8b rA1 = *(const s8b*)&rhT[cl * 72 + 32 + cg * 8];
  f4 ah[3];
#pragma unroll
  for (int nt = 0; nt < 3; ++nt) {
    f4 ch = {bfu(cxc[6 + nt].x), bfu(cxc[6 + nt].y), bfu(cxc[6 + nt].z), bfu(cxc[6 + nt].w)};
    ch = __builtin_amdgcn_mfma_f32_16x16x32_bf16(rA0, Whc[nt][0], ch, 0, 0, 0);
    ch = __builtin_amdgcn_mfma_f32_16x16x32_bf16(rA1, Whc[nt][1], ch, 0, 0, 0);
    ah[nt] = ch;
  }
#pragma unroll
  for (int nt = 0; nt < 3; ++nt)
#pragma unroll
    for (int r = 0; r < 4; ++r) {
      float hn = (1.f - z[nt][r]) * ho[nt][r] + z[nt][r] * tanh_(ah[nt][r]);
      ho[nt][r] = hn;
      hT[(cg * 4 + r) * 72 + nt * 16 + cl] = f2u(hn);
    }
  asm volatile("" ::: "memory");
  if (PF) {
#pragma unroll
    for (int nt = 0; nt < 3; ++nt)
#pragma unroll
      for (int c = 0; c < 2; ++c) {
        PIN(Wzn[nt][c]); PIN(Wrn[nt][c]); PIN(Whn[nt][c]);
      }
#pragma unroll
    for (int gn = 0; gn < 9; ++gn) PIN(cxn[gn]);
  }
}

template <typename TI, typename TO>
__device__ __forceinline__ void gru13_body(
    unsigned short* hT, unsigned short* rhT,
    const unsigned short* xfrag, const unsigned short* pwb,
    const TI* Wout, const TI* bout, TO* out) {
  int l = threadIdx.x;          // 64
  int cg = l >> 4, cl = l & 15;
  int blk = blockIdx.x;
  int b = blk / 50;
  int n0 = (blk % 50) * 16;

  for (int e = l; e < 1152; e += 64) { hT[e] = 0; rhT[e] = 0; }
  float bo = ldc(bout, 0);
  s8b WoB0, WoB1;
#pragma unroll
  for (int j = 0; j < 8; ++j) {
    int k0 = cg * 8 + j;
    int k1 = 32 + cg * 8 + j;
    WoB0[j] = (cl == 0) ? (short)f2u(ldc(Wout, k0)) : (short)0;
    WoB1[j] = (cl == 0 && k1 < 48) ? (short)f2u(ldc(Wout, k1)) : (short)0;
  }
  float ho[3][4];
#pragma unroll
  for (int nt = 0; nt < 3; ++nt)
#pragma unroll
    for (int r = 0; r < 4; ++r) ho[nt][r] = 0.f;

  const unsigned short* xg = xfrag + (size_t)blk * 48384;
  s8b WzA[3][2], WrA[3][2], WhA[3][2];
  s8b WzB[3][2], WrB[3][2], WhB[3][2];
  ushort4 cxA[9], cxB[9];
  {
    const unsigned short* pb = pwb + (size_t)l * 8;
#pragma unroll
    for (int nt = 0; nt < 3; ++nt)
#pragma unroll
      for (int c = 0; c < 2; ++c) {
        WzA[nt][c] = *(const s8b*)(pb + 0 * 3072 + nt * 1024 + c * 512);
        WrA[nt][c] = *(const s8b*)(pb + 1 * 3072 + nt * 1024 + c * 512);
        WhA[nt][c] = *(const s8b*)(pb + 2 * 3072 + nt * 1024 + c * 512);
      }
#pragma unroll
    for (int gn = 0; gn < 9; ++gn)
      cxA[gn] = *(const ushort4*)(xg + gn * 256 + l * 4);
  }
  asm volatile("" ::: "memory");

#pragma unroll 1
  for (int s2 = 0; s2 < 10; ++s2) {
    gru_step13<true>(2 * s2, l, cg, cl, b, n0,
                     WzA, WrA, WhA, cxA, WzB, WrB, WhB, cxB,
                     pwb, xg, hT, rhT, ho, WoB0, WoB1, bo, out);
    gru_step13<true>(2 * s2 + 1, l, cg, cl, b, n0,
                     WzB, WrB, WhB, cxB, WzA, WrA, WhA, cxA,
                     pwb, xg, hT, rhT, ho, WoB0, WoB1, bo, out);
  }
  gru_step13<false>(20, l, cg, cl, b, n0,
                    WzA, WrA, WhA, cxA, WzB, WrB, WhB, cxB,
                    pwb, xg, hT, rhT, ho, WoB0, WoB1, bo, out);
  {
    s8b hA0 = *(const s8b*)&hT[cl * 72 + cg * 8];
    s8b hA1 = *(const s8b*)&hT[cl * 72 + 32 + cg * 8];
    f4 oacc = {bo, bo, bo, bo};
    oacc = __builtin_amdgcn_mfma_f32_16x16x32_bf16(hA0, WoB0, oacc, 0, 0, 0);
    oacc = __builtin_amdgcn_mfma_f32_16x16x32_bf16(hA1, WoB1, oacc, 0, 0, 0);
    if (cl == 0) {
#pragma unroll
      for (int r = 0; r < 4; ++r)
        sto(out, ((size_t)b * TP_ + 9) * N_ + n0 + cg * 4 + r, oacc[r]);
    }
  }
}
__global__ __launch_bounds__(64, 1) void k_gru13(
    const void* xin, const bf16* xfrag, const bf16* pwb,
    const void* Wout, const void* bout, void* out) {
  __shared__ alignas(16) unsigned short hT[1152];
  __shared__ alignas(16) unsigned short rhT[1152];
  int f32 = detect_f32(xin);
  if (f32)
    gru13_body<float, float>(hT, rhT,
                             (const unsigned short*)xfrag, (const unsigned short*)pwb,
                             (const float*)Wout, (const float*)bout, (float*)out);
  else
    gru13_body<bf16, bf16>(hT, rhT,
                           (const unsigned short*)xfrag, (const unsigned short*)pwb,
                           (const bf16*)Wout, (const bf16*)bout, (bf16*)out);
}

// ---------------------------------------------------------------------------
extern "C" void kernel_launch(void* const* d_in, const int* in_sizes, int n_in,
                              void* d_out, int out_size, void* d_ws, size_t ws_size,
                              hipStream_t stream) {
  (void)in_sizes; (void)n_in; (void)out_size; (void)ws_size;
  const void* x       = d_in[0];
  const void* T       = d_in[1];
  const void* Wq_t    = d_in[3];
  const void* Wk_t    = d_in[4];
  const void* Wv_t    = d_in[5];
  const void* Wq_st   = d_in[6];
  const void* Wk_st   = d_in[7];
  const void* Wv_st   = d_in[8];
  const void* bq_t    = d_in[9];
  const void* bk_t    = d_in[10];
  const void* bv_t    = d_in[11];
  const void* bq_st   = d_in[12];
  const void* bk_st   = d_in[13];
  const void* bv_st   = d_in[14];
  const void* conv1_w = d_in[15];
  const void* conv1_b = d_in[16];
  const void* Wproj_t = d_in[17];
  const void* bproj_t = d_in[18];
  const void* Wproj_st= d_in[19];
  const void* bproj_st= d_in[20];
  const void* xhr_wz  = d_in[21];
  const void* xhr_wr  = d_in[22];
  const void* xhr_wh  = d_in[23];
  const void* xhr_bz  = d_in[24];
  const void* xhr_br  = d_in[25];
  const void* xhr_bh  = d_in[26];
  const void* last_wz = d_in[27];
  const void* last_wr = d_in[28];
  const void* last_wh = d_in[29];
  const void* last_bz = d_in[30];
  const void* last_br = d_in[31];
  const void* last_bh = d_in[32];
  const void* Wout    = d_in[33];
  const void* bout    = d_in[34];

  // ws layout (~13.9 MB; 14.75 MB proven safe earlier)
  char* wsb = (char*)d_ws;
  bf16* att_t  = (bf16*)(wsb + 256);
  bf16* att_st = att_t + (size_t)2 * 11 * 800 * 48;
  bf16* xfrag  = att_st + (size_t)2 * 11 * 800 * 48;
  bf16* pwb    = xfrag + (size_t)100 * 21 * 9 * 64 * 4;

  k_phase1<<<SP_BLKS + TMP_BLKS + PK_BLKS, 832, 0, stream>>>(
      x, Wq_t, Wk_t, Wv_t, bq_t, bk_t, bv_t,
      Wq_st, Wk_st, Wv_st, bq_st, bk_st, bv_st,
      xhr_wz, xhr_wr, xhr_wh, last_wz, last_wr, last_wh,
      Wproj_t, Wproj_st,
      att_t, att_st, pwb);
  k_xc<<<PJ_BLKS + CV_BLKS, 192, 0, stream>>>(
      att_t, att_st, bproj_t, bproj_st,
      xhr_bz, xhr_br, xhr_bh,
      x, T, conv1_w, conv1_b, last_bz, last_br, last_bh,
      pwb, xfrag);
  k_gru13<<<100, 64, 0, stream>>>(
      x, xfrag, pwb, Wout, bout, d_out);
}